// Round 4
// baseline (1053.387 us; speedup 1.0000x reference)
//
#include <hip/hip_runtime.h>
#include <hip/hip_bf16.h>

// GraphSAGE forward, 2 layers, f32.
// N=100000 nodes, E=1600000 edges, F=64 features, W: [128,64].

constexpr int N_NODES = 100000;
constexpr int N_EDGES = 1600000;
constexpr int F = 64;

// One 64-lane wave per edge. Gather x[src] row (256B coalesced), atomicAdd
// into agg[dst] row. Lane 0 also bumps the degree counter (only when cnt!=null).
__global__ void __launch_bounds__(256)
scatter_kernel(const float* __restrict__ x,
               const int* __restrict__ esrc,
               const int* __restrict__ edst,
               float* __restrict__ agg,
               float* __restrict__ cnt) {
    int e = blockIdx.x * (blockDim.x >> 6) + (threadIdx.x >> 6);
    int f = threadIdx.x & 63;
    if (e >= N_EDGES) return;
    int s = esrc[e];
    int d = edst[e];
    float v = x[(long long)s * F + f];
    atomicAdd(&agg[(long long)d * F + f], v);
    if (cnt != nullptr && f == 0) atomicAdd(&cnt[d], 1.0f);
}

// Fused concat + GEMV + bias + ReLU.
// Block = 256 threads = 4 waves; each wave owns one node; each lane owns one
// output feature j. W (128x64 = 32KB) staged in LDS, shared across the block.
__global__ void __launch_bounds__(256)
sage_layer_kernel(const float* __restrict__ xin,
                  const float* __restrict__ agg,
                  const float* __restrict__ cnt,
                  const float* __restrict__ W,
                  const float* __restrict__ bias,
                  float* __restrict__ out) {
    __shared__ float sW[2 * F * F];   // 128 x 64
    __shared__ float sb[F];
    __shared__ float sin[4][2 * F];   // per-wave concat input

    for (int i = threadIdx.x; i < 2 * F * F; i += 256) sW[i] = W[i];
    if (threadIdx.x < F) sb[threadIdx.x] = bias[threadIdx.x];

    int w = threadIdx.x >> 6;   // wave in block -> node
    int j = threadIdx.x & 63;   // output feature
    int n = blockIdx.x * 4 + w;

    if (n < N_NODES) {
        float c = cnt[n];
        float scale = 1.0f / fmaxf(c, 1.0f);
        sin[w][j]     = xin[(long long)n * F + j];
        sin[w][F + j] = agg[(long long)n * F + j] * scale;
    }
    __syncthreads();

    if (n < N_NODES) {
        float sum = sb[j];
        #pragma unroll
        for (int k = 0; k < 2 * F; ++k) {
            sum += sin[w][k] * sW[k * F + j];   // sin broadcast; sW coalesced
        }
        out[(long long)n * F + j] = fmaxf(sum, 0.0f);
    }
}

extern "C" void kernel_launch(void* const* d_in, const int* in_sizes, int n_in,
                              void* d_out, int out_size, void* d_ws, size_t ws_size,
                              hipStream_t stream) {
    const float* x    = (const float*)d_in[0];
    const int*   esrc = (const int*)d_in[1];
    const int*   edst = (const int*)d_in[2];
    const float* W1   = (const float*)d_in[3];
    const float* b1   = (const float*)d_in[4];
    const float* W2   = (const float*)d_in[5];
    const float* b2   = (const float*)d_in[6];
    float* out = (float*)d_out;

    float* agg = (float*)d_ws;                       // N*F floats = 25.6 MB
    float* cnt = agg + (size_t)N_NODES * F;          // N floats

    const int EDGE_BLOCKS = (N_EDGES + 3) / 4;       // 4 edges (waves) per block
    const int NODE_BLOCKS = (N_NODES + 3) / 4;       // 4 nodes per block

    // ---- layer 1 ----
    hipMemsetAsync(agg, 0, ((size_t)N_NODES * F + N_NODES) * sizeof(float), stream);
    scatter_kernel<<<EDGE_BLOCKS, 256, 0, stream>>>(x, esrc, edst, agg, cnt);
    sage_layer_kernel<<<NODE_BLOCKS, 256, 0, stream>>>(x, agg, cnt, W1, b1, out);

    // ---- layer 2 (reuse cnt; reset agg only) ----
    hipMemsetAsync(agg, 0, (size_t)N_NODES * F * sizeof(float), stream);
    scatter_kernel<<<EDGE_BLOCKS, 256, 0, stream>>>(out, esrc, edst, agg, nullptr);
    sage_layer_kernel<<<NODE_BLOCKS, 256, 0, stream>>>(out, agg, cnt, W2, b2, out);
}

// Round 5
// 776.584 us; speedup vs baseline: 1.3564x; 1.3564x over previous
//
#include <hip/hip_runtime.h>
#include <hip/hip_bf16.h>

// GraphSAGE forward, 2 layers, f32.
// N=100000 nodes, E=1600000 edges, F=64, W: [128,64].
//
// Round 5 strategy: the round-4 profile showed 81% of time in the atomic
// scatter (450 MB HBM WRITE per layer: device-scope f32 atomics resolve past
// the non-coherent per-XCD L2s, so each of 102.4M atomicAdds is an HBM-side
// RMW). Replace with on-the-fly CSR build (1.6M int atomics total) + fused
// gather-aggregate + GEMV + ReLU per layer (no agg buffer, no big memsets).

constexpr int N_NODES = 100000;
constexpr int N_EDGES = 1600000;
constexpr int F = 64;

// ---------------------------------------------------------------------------
// CSR build
// ---------------------------------------------------------------------------

__global__ void __launch_bounds__(256)
hist_kernel(const int* __restrict__ edst, int* __restrict__ deg) {
    int e = blockIdx.x * 256 + threadIdx.x;
    if (e < N_EDGES) atomicAdd(&deg[edst[e]], 1);
}

// Single-block exclusive scan over deg[N] -> rp[N+1]; also seeds cursor = rp.
__global__ void __launch_bounds__(1024)
scan_kernel(const int* __restrict__ deg, int* __restrict__ rp,
            int* __restrict__ cursor) {
    __shared__ int part[1024];
    const int T = 1024;
    const int CH = (N_NODES + T - 1) / T;          // 98
    int t = threadIdx.x;
    int lo = t * CH;
    int hi = lo + CH; if (hi > N_NODES) hi = N_NODES;
    if (lo > N_NODES) lo = N_NODES;

    int s = 0;
    for (int i = lo; i < hi; ++i) s += deg[i];
    part[t] = s;
    __syncthreads();
    // Hillis-Steele inclusive scan over 1024 partials.
    for (int off = 1; off < T; off <<= 1) {
        int v = part[t];
        int add = (t >= off) ? part[t - off] : 0;
        __syncthreads();
        part[t] = v + add;
        __syncthreads();
    }
    int run = (t == 0) ? 0 : part[t - 1];          // exclusive prefix of chunk
    for (int i = lo; i < hi; ++i) {
        rp[i] = run;
        cursor[i] = run;
        run += deg[i];
    }
    if (t == T - 1) rp[N_NODES] = run;             // = E (trailing chunks empty)
}

__global__ void __launch_bounds__(256)
fill_kernel(const int* __restrict__ esrc, const int* __restrict__ edst,
            int* __restrict__ cursor, int* __restrict__ ss) {
    int e = blockIdx.x * 256 + threadIdx.x;
    if (e >= N_EDGES) return;
    int d = edst[e];
    int pos = atomicAdd(&cursor[d], 1);
    ss[pos] = esrc[e];
}

// ---------------------------------------------------------------------------
// Fused layer: gather-aggregate (CSR) + concat + GEMV + bias + ReLU.
// Block = 512 threads = 8 waves; one node per wave; lane = feature.
// W (128x64 = 32 KB) staged in LDS once per block.
// ---------------------------------------------------------------------------
__global__ void __launch_bounds__(512)
fused_sage_kernel(const float* __restrict__ xin,
                  const int* __restrict__ rp,
                  const int* __restrict__ ss,
                  const float* __restrict__ W,
                  const float* __restrict__ bias,
                  float* __restrict__ out) {
    __shared__ float sW[2 * F * F];     // 128 x 64
    __shared__ float sb[F];
    __shared__ float sin_[8][2 * F];

    for (int i = threadIdx.x; i < 2 * F * F; i += 512) sW[i] = W[i];
    if (threadIdx.x < F) sb[threadIdx.x] = bias[threadIdx.x];

    int w = threadIdx.x >> 6;
    int f = threadIdx.x & 63;
    int n = blockIdx.x * 8 + w;

    if (n < N_NODES) {
        int start = rp[n];
        int end   = rp[n + 1];
        float acc = 0.0f;
        int i = start;
        // 4-wide batches: 4 independent row loads in flight per iteration.
        for (; i + 4 <= end; i += 4) {
            int s0 = ss[i], s1 = ss[i + 1], s2 = ss[i + 2], s3 = ss[i + 3];
            float a0 = xin[(size_t)s0 * F + f];
            float a1 = xin[(size_t)s1 * F + f];
            float a2 = xin[(size_t)s2 * F + f];
            float a3 = xin[(size_t)s3 * F + f];
            acc += a0 + a1 + a2 + a3;
        }
        for (; i < end; ++i) acc += xin[(size_t)ss[i] * F + f];
        float degf  = (float)(end - start);
        float scale = 1.0f / fmaxf(degf, 1.0f);
        sin_[w][f]     = xin[(size_t)n * F + f];
        sin_[w][F + f] = acc * scale;
    }
    __syncthreads();

    if (n < N_NODES) {
        float sum = sb[f];
        #pragma unroll
        for (int k = 0; k < 2 * F; ++k) {
            sum += sin_[w][k] * sW[k * F + f];   // sin broadcast; sW 2-way free
        }
        out[(size_t)n * F + f] = fmaxf(sum, 0.0f);
    }
}

// ---------------------------------------------------------------------------
// Fallback path (round-4 measured-correct atomic version), used only if the
// workspace is too small for the CSR path. ws_size is constant across calls,
// so the branch is graph-capture-safe.
// ---------------------------------------------------------------------------
__global__ void __launch_bounds__(256)
scatter_kernel(const float* __restrict__ x,
               const int* __restrict__ esrc,
               const int* __restrict__ edst,
               float* __restrict__ agg,
               float* __restrict__ cnt) {
    int e = blockIdx.x * (blockDim.x >> 6) + (threadIdx.x >> 6);
    int f = threadIdx.x & 63;
    if (e >= N_EDGES) return;
    int s = esrc[e];
    int d = edst[e];
    float v = x[(long long)s * F + f];
    atomicAdd(&agg[(long long)d * F + f], v);
    if (cnt != nullptr && f == 0) atomicAdd(&cnt[d], 1.0f);
}

__global__ void __launch_bounds__(256)
sage_layer_kernel(const float* __restrict__ xin,
                  const float* __restrict__ agg,
                  const float* __restrict__ cnt,
                  const float* __restrict__ W,
                  const float* __restrict__ bias,
                  float* __restrict__ out) {
    __shared__ float sW[2 * F * F];
    __shared__ float sb[F];
    __shared__ float sin_[4][2 * F];

    for (int i = threadIdx.x; i < 2 * F * F; i += 256) sW[i] = W[i];
    if (threadIdx.x < F) sb[threadIdx.x] = bias[threadIdx.x];

    int w = threadIdx.x >> 6;
    int j = threadIdx.x & 63;
    int n = blockIdx.x * 4 + w;

    if (n < N_NODES) {
        float c = cnt[n];
        float scale = 1.0f / fmaxf(c, 1.0f);
        sin_[w][j]     = xin[(long long)n * F + j];
        sin_[w][F + j] = agg[(long long)n * F + j] * scale;
    }
    __syncthreads();

    if (n < N_NODES) {
        float sum = sb[j];
        #pragma unroll
        for (int k = 0; k < 2 * F; ++k) sum += sin_[w][k] * sW[k * F + j];
        out[(long long)n * F + j] = fmaxf(sum, 0.0f);
    }
}

extern "C" void kernel_launch(void* const* d_in, const int* in_sizes, int n_in,
                              void* d_out, int out_size, void* d_ws, size_t ws_size,
                              hipStream_t stream) {
    const float* x    = (const float*)d_in[0];
    const int*   esrc = (const int*)d_in[1];
    const int*   edst = (const int*)d_in[2];
    const float* W1   = (const float*)d_in[3];
    const float* b1   = (const float*)d_in[4];
    const float* W2   = (const float*)d_in[5];
    const float* b2   = (const float*)d_in[6];
    float* out = (float*)d_out;

    // CSR-path workspace layout.
    const size_t csr_bytes =
        (size_t)(N_NODES            /* deg    */
               + N_NODES + 1        /* rp     */
               + N_NODES            /* cursor */
               + N_EDGES) * 4       /* ss     */
        + (size_t)N_NODES * F * 4;  /* h1     */

    if (ws_size >= csr_bytes) {
        int* deg    = (int*)d_ws;
        int* rp     = deg + N_NODES;
        int* cursor = rp + N_NODES + 1;
        int* ss     = cursor + N_NODES;
        float* h1   = (float*)(ss + N_EDGES);

        const int EB = (N_EDGES + 255) / 256;        // 6250
        const int NB = (N_NODES + 7) / 8;            // 12500

        hipMemsetAsync(deg, 0, (size_t)N_NODES * 4, stream);
        hist_kernel<<<EB, 256, 0, stream>>>(edst, deg);
        scan_kernel<<<1, 1024, 0, stream>>>(deg, rp, cursor);
        fill_kernel<<<EB, 256, 0, stream>>>(esrc, edst, cursor, ss);

        fused_sage_kernel<<<NB, 512, 0, stream>>>(x,  rp, ss, W1, b1, h1);
        fused_sage_kernel<<<NB, 512, 0, stream>>>(h1, rp, ss, W2, b2, out);
    } else {
        // Fallback: measured-correct atomic path (round 4).
        float* agg = (float*)d_ws;
        float* cnt = agg + (size_t)N_NODES * F;
        const int EDGE_BLOCKS = (N_EDGES + 3) / 4;
        const int NODE_BLOCKS = (N_NODES + 3) / 4;

        hipMemsetAsync(agg, 0, ((size_t)N_NODES * F + N_NODES) * 4, stream);
        scatter_kernel<<<EDGE_BLOCKS, 256, 0, stream>>>(x, esrc, edst, agg, cnt);
        sage_layer_kernel<<<NODE_BLOCKS, 256, 0, stream>>>(x, agg, cnt, W1, b1, out);

        hipMemsetAsync(agg, 0, (size_t)N_NODES * F * 4, stream);
        scatter_kernel<<<EDGE_BLOCKS, 256, 0, stream>>>(out, esrc, edst, agg, nullptr);
        sage_layer_kernel<<<NODE_BLOCKS, 256, 0, stream>>>(out, agg, cnt, W2, b2, out);
    }
}

// Round 6
// 550.905 us; speedup vs baseline: 1.9121x; 1.4097x over previous
//
#include <hip/hip_runtime.h>
#include <hip/hip_bf16.h>

// GraphSAGE forward, 2 layers, f32.
// N=100000 nodes, E=1600000 edges, F=64, W: [128,64].
//
// Round 6: round-5 profile showed scan_kernel (single-block scan) = 229 us,
// 30% of total, 0.15% occupancy. Replace with 3-phase parallel scan
// (block partials -> tiny scan of 98 sums -> apply). Rest unchanged.

constexpr int N_NODES = 100000;
constexpr int N_EDGES = 1600000;
constexpr int F = 64;
constexpr int N4 = N_NODES / 4;               // 25000 int4s (N divisible by 4)
constexpr int SCAN_BLOCKS = (N4 + 255) / 256; // 98

// ---------------------------------------------------------------------------
// CSR build
// ---------------------------------------------------------------------------

__global__ void __launch_bounds__(256)
hist_kernel(const int* __restrict__ edst, int* __restrict__ deg) {
    int e = blockIdx.x * 256 + threadIdx.x;
    if (e < N_EDGES) atomicAdd(&deg[edst[e]], 1);
}

// Phase A: per-block (1024-elem chunk) sums via int4 loads + LDS tree reduce.
__global__ void __launch_bounds__(256)
partial_kernel(const int* __restrict__ deg, int* __restrict__ bsum) {
    __shared__ int red[256];
    int t = threadIdx.x;
    int gi = blockIdx.x * 256 + t;            // int4 index
    int s = 0;
    if (gi < N4) {
        int4 v = ((const int4*)deg)[gi];
        s = v.x + v.y + v.z + v.w;
    }
    red[t] = s;
    __syncthreads();
    for (int off = 128; off > 0; off >>= 1) {
        if (t < off) red[t] += red[t + off];
        __syncthreads();
    }
    if (t == 0) bsum[blockIdx.x] = red[0];
}

// Phase B: exclusive scan of the 98 block sums (LDS-serial, ~5us); rp[N]=E.
__global__ void __launch_bounds__(128)
scan_bsums_kernel(const int* __restrict__ bsum, int* __restrict__ boff,
                  int* __restrict__ rp) {
    __shared__ int s[SCAN_BLOCKS];
    int t = threadIdx.x;
    if (t < SCAN_BLOCKS) s[t] = bsum[t];
    __syncthreads();
    if (t == 0) {
        int run = 0;
        for (int i = 0; i < SCAN_BLOCKS; ++i) { int v = s[i]; s[i] = run; run += v; }
        rp[N_NODES] = run;
    }
    __syncthreads();
    if (t < SCAN_BLOCKS) boff[t] = s[t];
}

// Phase C: per-block exclusive scan (int4 + 256-wide Hillis-Steele) + offset;
// writes rp[0..N) and cursor[0..N) as int4.
__global__ void __launch_bounds__(256)
scan_apply_kernel(const int* __restrict__ deg, const int* __restrict__ boff,
                  int* __restrict__ rp, int* __restrict__ cursor) {
    __shared__ int sc[256];
    int t = threadIdx.x;
    int gi = blockIdx.x * 256 + t;
    int4 v = make_int4(0, 0, 0, 0);
    if (gi < N4) v = ((const int4*)deg)[gi];
    int s = v.x + v.y + v.z + v.w;
    sc[t] = s;
    __syncthreads();
    for (int off = 1; off < 256; off <<= 1) {
        int val = sc[t];
        int add = (t >= off) ? sc[t - off] : 0;
        __syncthreads();
        sc[t] = val + add;
        __syncthreads();
    }
    if (gi < N4) {
        int prefix = boff[blockIdx.x] + ((t == 0) ? 0 : sc[t - 1]);
        int4 r;
        r.x = prefix;
        r.y = r.x + v.x;
        r.z = r.y + v.y;
        r.w = r.z + v.z;
        ((int4*)rp)[gi] = r;
        ((int4*)cursor)[gi] = r;
    }
}

__global__ void __launch_bounds__(256)
fill_kernel(const int* __restrict__ esrc, const int* __restrict__ edst,
            int* __restrict__ cursor, int* __restrict__ ss) {
    int e = blockIdx.x * 256 + threadIdx.x;
    if (e >= N_EDGES) return;
    int d = edst[e];
    int pos = atomicAdd(&cursor[d], 1);
    ss[pos] = esrc[e];
}

// ---------------------------------------------------------------------------
// Fused layer: gather-aggregate (CSR) + concat + GEMV + bias + ReLU.
// Block = 512 threads = 8 waves; one node per wave; lane = feature.
// W (128x64 = 32 KB) staged in LDS once per block.
// ---------------------------------------------------------------------------
__global__ void __launch_bounds__(512)
fused_sage_kernel(const float* __restrict__ xin,
                  const int* __restrict__ rp,
                  const int* __restrict__ ss,
                  const float* __restrict__ W,
                  const float* __restrict__ bias,
                  float* __restrict__ out) {
    __shared__ float sW[2 * F * F];     // 128 x 64
    __shared__ float sb[F];
    __shared__ float sin_[8][2 * F];

    for (int i = threadIdx.x; i < 2 * F * F; i += 512) sW[i] = W[i];
    if (threadIdx.x < F) sb[threadIdx.x] = bias[threadIdx.x];

    int w = threadIdx.x >> 6;
    int f = threadIdx.x & 63;
    int n = blockIdx.x * 8 + w;

    if (n < N_NODES) {
        int start = rp[n];
        int end   = rp[n + 1];
        float acc = 0.0f;
        int i = start;
        for (; i + 4 <= end; i += 4) {
            int s0 = ss[i], s1 = ss[i + 1], s2 = ss[i + 2], s3 = ss[i + 3];
            float a0 = xin[(size_t)s0 * F + f];
            float a1 = xin[(size_t)s1 * F + f];
            float a2 = xin[(size_t)s2 * F + f];
            float a3 = xin[(size_t)s3 * F + f];
            acc += a0 + a1 + a2 + a3;
        }
        for (; i < end; ++i) acc += xin[(size_t)ss[i] * F + f];
        float degf  = (float)(end - start);
        float scale = 1.0f / fmaxf(degf, 1.0f);
        sin_[w][f]     = xin[(size_t)n * F + f];
        sin_[w][F + f] = acc * scale;
    }
    __syncthreads();

    if (n < N_NODES) {
        float sum = sb[f];
        #pragma unroll
        for (int k = 0; k < 2 * F; ++k) {
            sum += sin_[w][k] * sW[k * F + f];
        }
        out[(size_t)n * F + f] = fmaxf(sum, 0.0f);
    }
}

extern "C" void kernel_launch(void* const* d_in, const int* in_sizes, int n_in,
                              void* d_out, int out_size, void* d_ws, size_t ws_size,
                              hipStream_t stream) {
    const float* x    = (const float*)d_in[0];
    const int*   esrc = (const int*)d_in[1];
    const int*   edst = (const int*)d_in[2];
    const float* W1   = (const float*)d_in[3];
    const float* b1   = (const float*)d_in[4];
    const float* W2   = (const float*)d_in[5];
    const float* b2   = (const float*)d_in[6];
    float* out = (float*)d_out;

    // Workspace layout (all 16B-aligned blocks):
    // deg[100000] cursor[100000] rp[100004] ss[1600000] h1[6400000] bsum[128] boff[128]
    int*   deg    = (int*)d_ws;
    int*   cursor = deg + N_NODES;
    int*   rp     = cursor + N_NODES;
    int*   ss     = rp + (N_NODES + 4);
    float* h1     = (float*)(ss + N_EDGES);
    int*   bsum   = (int*)(h1 + (size_t)N_NODES * F);
    int*   boff   = bsum + 128;

    const int EB = (N_EDGES + 255) / 256;        // 6250
    const int NB = (N_NODES + 7) / 8;            // 12500

    hipMemsetAsync(deg, 0, (size_t)N_NODES * 4, stream);
    hist_kernel<<<EB, 256, 0, stream>>>(edst, deg);
    partial_kernel<<<SCAN_BLOCKS, 256, 0, stream>>>(deg, bsum);
    scan_bsums_kernel<<<1, 128, 0, stream>>>(bsum, boff, rp);
    scan_apply_kernel<<<SCAN_BLOCKS, 256, 0, stream>>>(deg, boff, rp, cursor);
    fill_kernel<<<EB, 256, 0, stream>>>(esrc, edst, cursor, ss);

    fused_sage_kernel<<<NB, 512, 0, stream>>>(x,  rp, ss, W1, b1, h1);
    fused_sage_kernel<<<NB, 512, 0, stream>>>(h1, rp, ss, W2, b2, out);
}

// Round 7
// 528.291 us; speedup vs baseline: 1.9940x; 1.0428x over previous
//
#include <hip/hip_runtime.h>
#include <hip/hip_bf16.h>

// GraphSAGE forward, 2 layers. N=100000, E=1600000, F=64, W: [128,64].
//
// Round 7: round-6 profile: fused_sage = 2x151 us (55%), FETCH 267 MB vs
// 25.6 MB x => gather over-fetch / latency bound. Lever: bf16 feature
// storage for the gather (halves bytes + footprint), pair-load layout
// (lanes 0-31 edge i, lanes 32-63 edge i+1, one uint = 2 features).
// GEMV stays f32. CSR build unchanged from round 6.

constexpr int N_NODES = 100000;
constexpr int N_EDGES = 1600000;
constexpr int F = 64;
constexpr int N4 = N_NODES / 4;               // 25000
constexpr int SCAN_BLOCKS = (N4 + 255) / 256; // 98

// ---- bf16 helpers (RN-even; inputs are finite) ----
__device__ __forceinline__ float bf2f(ushort u) {
    union { unsigned int i; float f; } c; c.i = (unsigned int)u << 16; return c.f;
}
__device__ __forceinline__ ushort f2bf(float v) {
    union { float f; unsigned int i; } c; c.f = v;
    unsigned int r = c.i + 0x7fffu + ((c.i >> 16) & 1u);
    return (ushort)(r >> 16);
}

// ---------------------------------------------------------------------------
// CSR build (unchanged from round 6)
// ---------------------------------------------------------------------------

__global__ void __launch_bounds__(256)
hist_kernel(const int* __restrict__ edst, int* __restrict__ deg) {
    int e = blockIdx.x * 256 + threadIdx.x;
    if (e < N_EDGES) atomicAdd(&deg[edst[e]], 1);
}

__global__ void __launch_bounds__(256)
partial_kernel(const int* __restrict__ deg, int* __restrict__ bsum) {
    __shared__ int red[256];
    int t = threadIdx.x;
    int gi = blockIdx.x * 256 + t;
    int s = 0;
    if (gi < N4) {
        int4 v = ((const int4*)deg)[gi];
        s = v.x + v.y + v.z + v.w;
    }
    red[t] = s;
    __syncthreads();
    for (int off = 128; off > 0; off >>= 1) {
        if (t < off) red[t] += red[t + off];
        __syncthreads();
    }
    if (t == 0) bsum[blockIdx.x] = red[0];
}

__global__ void __launch_bounds__(128)
scan_bsums_kernel(const int* __restrict__ bsum, int* __restrict__ boff,
                  int* __restrict__ rp) {
    __shared__ int s[SCAN_BLOCKS];
    int t = threadIdx.x;
    if (t < SCAN_BLOCKS) s[t] = bsum[t];
    __syncthreads();
    if (t == 0) {
        int run = 0;
        for (int i = 0; i < SCAN_BLOCKS; ++i) { int v = s[i]; s[i] = run; run += v; }
        rp[N_NODES] = run;
    }
    __syncthreads();
    if (t < SCAN_BLOCKS) boff[t] = s[t];
}

__global__ void __launch_bounds__(256)
scan_apply_kernel(const int* __restrict__ deg, const int* __restrict__ boff,
                  int* __restrict__ rp, int* __restrict__ cursor) {
    __shared__ int sc[256];
    int t = threadIdx.x;
    int gi = blockIdx.x * 256 + t;
    int4 v = make_int4(0, 0, 0, 0);
    if (gi < N4) v = ((const int4*)deg)[gi];
    int s = v.x + v.y + v.z + v.w;
    sc[t] = s;
    __syncthreads();
    for (int off = 1; off < 256; off <<= 1) {
        int val = sc[t];
        int add = (t >= off) ? sc[t - off] : 0;
        __syncthreads();
        sc[t] = val + add;
        __syncthreads();
    }
    if (gi < N4) {
        int prefix = boff[blockIdx.x] + ((t == 0) ? 0 : sc[t - 1]);
        int4 r;
        r.x = prefix;
        r.y = r.x + v.x;
        r.z = r.y + v.y;
        r.w = r.z + v.z;
        ((int4*)rp)[gi] = r;
        ((int4*)cursor)[gi] = r;
    }
}

__global__ void __launch_bounds__(256)
fill_kernel(const int* __restrict__ esrc, const int* __restrict__ edst,
            int* __restrict__ cursor, int* __restrict__ ss) {
    int e = blockIdx.x * 256 + threadIdx.x;
    if (e >= N_EDGES) return;
    int d = edst[e];
    int pos = atomicAdd(&cursor[d], 1);
    ss[pos] = esrc[e];
}

// ---------------------------------------------------------------------------
// f32 -> bf16 conversion of the input features (N*F/4 float4s, exact grid)
// ---------------------------------------------------------------------------
__global__ void __launch_bounds__(256)
conv_kernel(const float* __restrict__ x, ushort* __restrict__ xh) {
    int i = blockIdx.x * 256 + threadIdx.x;    // float4 index; grid covers exactly
    float4 v = ((const float4*)x)[i];
    ushort4 o;
    o.x = f2bf(v.x); o.y = f2bf(v.y); o.z = f2bf(v.z); o.w = f2bf(v.w);
    ((ushort4*)xh)[i] = o;
}

// ---------------------------------------------------------------------------
// Fused layer: CSR gather-mean (bf16 rows, pair-load) + concat + f32 GEMV.
// Block = 512 = 8 waves; one node per wave.
// Lane l: half = l>>5 (edge parity), p = l&31 (feature pair 2p,2p+1).
// One uint load = 2 bf16 features; lanes 0-31 edge i, lanes 32-63 edge i+1.
// ---------------------------------------------------------------------------
__global__ void __launch_bounds__(512)
fused_sage_kernel(const ushort* __restrict__ xh,
                  const int* __restrict__ rp,
                  const int* __restrict__ ss,
                  const float* __restrict__ W,
                  const float* __restrict__ bias,
                  ushort* __restrict__ out_bf,   // layer-1 output (bf16) or null
                  float* __restrict__ out_f)     // layer-2 output (f32) or null
{
    __shared__ float sW[2 * F * F];     // 128 x 64
    __shared__ float sb[F];
    __shared__ float sin_[8][2 * F];

    for (int i = threadIdx.x; i < 2 * F * F; i += 512) sW[i] = W[i];
    if (threadIdx.x < F) sb[threadIdx.x] = bias[threadIdx.x];

    const int w    = threadIdx.x >> 6;
    const int lane = threadIdx.x & 63;
    const int half = lane >> 5;
    const int p    = lane & 31;
    const int n    = blockIdx.x * 8 + w;

    const unsigned int* __restrict__ xw = (const unsigned int*)xh; // row = 32 uints

    if (n < N_NODES) {
        int start = rp[n];
        int end   = rp[n + 1];
        float ax = 0.0f, ay = 0.0f;

        int i = start;
        // 8 edges per iteration: this half-wave covers edges i+half+{0,2,4,6}.
        for (; i + 8 <= end; i += 8) {
            int e0 = i + half;
            int s0 = ss[e0], s1 = ss[e0 + 2], s2 = ss[e0 + 4], s3 = ss[e0 + 6];
            unsigned int u0 = xw[(size_t)s0 * 32 + p];
            unsigned int u1 = xw[(size_t)s1 * 32 + p];
            unsigned int u2 = xw[(size_t)s2 * 32 + p];
            unsigned int u3 = xw[(size_t)s3 * 32 + p];
            ax += bf2f((ushort)u0) + bf2f((ushort)u1)
                + bf2f((ushort)u2) + bf2f((ushort)u3);
            ay += bf2f((ushort)(u0 >> 16)) + bf2f((ushort)(u1 >> 16))
                + bf2f((ushort)(u2 >> 16)) + bf2f((ushort)(u3 >> 16));
        }
        // pair tail
        for (; i + 2 <= end; i += 2) {
            int s0 = ss[i + half];
            unsigned int u0 = xw[(size_t)s0 * 32 + p];
            ax += bf2f((ushort)u0);
            ay += bf2f((ushort)(u0 >> 16));
        }
        // odd last edge: only half 0 contributes
        if (i < end && half == 0) {
            int s0 = ss[i];
            unsigned int u0 = xw[(size_t)s0 * 32 + p];
            ax += bf2f((ushort)u0);
            ay += bf2f((ushort)(u0 >> 16));
        }
        // combine the two half-wave accumulators
        ax += __shfl_xor(ax, 32);
        ay += __shfl_xor(ay, 32);

        float degf  = (float)(end - start);
        float scale = 1.0f / fmaxf(degf, 1.0f);
        if (half == 0) {
            sin_[w][F + 2 * p]     = ax * scale;
            sin_[w][F + 2 * p + 1] = ay * scale;
        }
        sin_[w][lane] = bf2f(xh[(size_t)n * F + lane]);   // self feature
    }
    __syncthreads();

    if (n < N_NODES) {
        const int f = lane;
        float sum = sb[f];
        #pragma unroll
        for (int k = 0; k < 2 * F; ++k) {
            sum += sin_[w][k] * sW[k * F + f];
        }
        float r = fmaxf(sum, 0.0f);
        if (out_bf) out_bf[(size_t)n * F + f] = f2bf(r);
        if (out_f)  out_f[(size_t)n * F + f]  = r;
    }
}

extern "C" void kernel_launch(void* const* d_in, const int* in_sizes, int n_in,
                              void* d_out, int out_size, void* d_ws, size_t ws_size,
                              hipStream_t stream) {
    const float* x    = (const float*)d_in[0];
    const int*   esrc = (const int*)d_in[1];
    const int*   edst = (const int*)d_in[2];
    const float* W1   = (const float*)d_in[3];
    const float* b1   = (const float*)d_in[4];
    const float* W2   = (const float*)d_in[5];
    const float* b2   = (const float*)d_in[6];
    float* out = (float*)d_out;

    // Workspace layout (16B-aligned blocks):
    int*    deg    = (int*)d_ws;
    int*    cursor = deg + N_NODES;
    int*    rp     = cursor + N_NODES;
    int*    ss     = rp + (N_NODES + 4);
    ushort* xh     = (ushort*)(ss + N_EDGES);            // bf16 x      (12.8 MB)
    ushort* h1h    = xh + (size_t)N_NODES * F;           // bf16 h1     (12.8 MB)
    int*    bsum   = (int*)(h1h + (size_t)N_NODES * F);
    int*    boff   = bsum + 128;

    const int EB = (N_EDGES + 255) / 256;        // 6250
    const int NB = (N_NODES + 7) / 8;            // 12500
    const int CB = (N_NODES * F / 4) / 256;      // 6250 (exact)

    hipMemsetAsync(deg, 0, (size_t)N_NODES * 4, stream);
    hist_kernel<<<EB, 256, 0, stream>>>(edst, deg);
    partial_kernel<<<SCAN_BLOCKS, 256, 0, stream>>>(deg, bsum);
    scan_bsums_kernel<<<1, 128, 0, stream>>>(bsum, boff, rp);
    scan_apply_kernel<<<SCAN_BLOCKS, 256, 0, stream>>>(deg, boff, rp, cursor);
    fill_kernel<<<EB, 256, 0, stream>>>(esrc, edst, cursor, ss);
    conv_kernel<<<CB, 256, 0, stream>>>(x, xh);

    fused_sage_kernel<<<NB, 512, 0, stream>>>(xh,  rp, ss, W1, b1, h1h, nullptr);
    fused_sage_kernel<<<NB, 512, 0, stream>>>(h1h, rp, ss, W2, b2, nullptr, out);
}

// Round 8
// 497.638 us; speedup vs baseline: 2.1168x; 1.0616x over previous
//
#include <hip/hip_runtime.h>
#include <hip/hip_bf16.h>

// GraphSAGE forward, 2 layers. N=100000, E=1600000, F=64, W: [128,64].
//
// Round 8: round-7 profile: fill_kernel = 133 us, WRITE_SIZE = 105 MB
// (1.6M random 4B stores -> one 64B line writeback each, across 8
// non-coherent L2s). Lever: dst-bucketed CSR fill. 16 buckets (dst>>13);
// part_kernel does an LDS counting-sort into a partitioned edge buffer
// (coalesced writes); fill2_kernel processes one bucket per blockIdx&15 so
// each bucket's cursor+ss slice (~0.55 MB) stays L2-resident on one XCD.
// ebuf aliases h1 (used before sage1 writes h1). Everything else unchanged.

constexpr int N_NODES = 100000;
constexpr int N_EDGES = 1600000;
constexpr int F = 64;
constexpr int N4 = N_NODES / 4;               // 25000
constexpr int SCAN_BLOCKS = (N4 + 255) / 256; // 98
constexpr int NBK = 16;                       // buckets (dst >> 13)
constexpr int PART_BLOCKS = (N_EDGES + 2047) / 2048; // 782
constexpr int FILL2_CHUNKS = 48;
constexpr int FILL2_BLOCKS = NBK * FILL2_CHUNKS;     // 768

// ---- bf16 helpers (RN-even; inputs are finite) ----
__device__ __forceinline__ float bf2f(ushort u) {
    union { unsigned int i; float f; } c; c.i = (unsigned int)u << 16; return c.f;
}
__device__ __forceinline__ ushort f2bf(float v) {
    union { float f; unsigned int i; } c; c.f = v;
    unsigned int r = c.i + 0x7fffu + ((c.i >> 16) & 1u);
    return (ushort)(r >> 16);
}

// ---------------------------------------------------------------------------
// CSR build
// ---------------------------------------------------------------------------

// deg histogram + 16-way bucket count in one edge pass.
__global__ void __launch_bounds__(256)
bucket_hist_kernel(const int* __restrict__ edst, int* __restrict__ deg,
                   int* __restrict__ bcnt) {
    __shared__ int lb[NBK];
    int t = threadIdx.x;
    if (t < NBK) lb[t] = 0;
    __syncthreads();
    int base = blockIdx.x * 2048;
    #pragma unroll
    for (int k = 0; k < 8; ++k) {
        int e = base + k * 256 + t;
        if (e < N_EDGES) {
            int d = edst[e];
            atomicAdd(&deg[d], 1);
            atomicAdd(&lb[d >> 13], 1);
        }
    }
    __syncthreads();
    if (t < NBK && lb[t]) atomicAdd(&bcnt[t], lb[t]);
}

__global__ void __launch_bounds__(256)
partial_kernel(const int* __restrict__ deg, int* __restrict__ bsum) {
    __shared__ int red[256];
    int t = threadIdx.x;
    int gi = blockIdx.x * 256 + t;
    int s = 0;
    if (gi < N4) {
        int4 v = ((const int4*)deg)[gi];
        s = v.x + v.y + v.z + v.w;
    }
    red[t] = s;
    __syncthreads();
    for (int off = 128; off > 0; off >>= 1) {
        if (t < off) red[t] += red[t + off];
        __syncthreads();
    }
    if (t == 0) bsum[blockIdx.x] = red[0];
}

// Scan of 98 block sums (rp base) + scan of 16 bucket counts (ebuf base).
__global__ void __launch_bounds__(128)
scan_bsums_kernel(const int* __restrict__ bsum, int* __restrict__ boff,
                  int* __restrict__ rp,
                  const int* __restrict__ bcnt, int* __restrict__ bbase,
                  int* __restrict__ bcur) {
    __shared__ int s[SCAN_BLOCKS];
    int t = threadIdx.x;
    if (t < SCAN_BLOCKS) s[t] = bsum[t];
    __syncthreads();
    if (t == 0) {
        int run = 0;
        for (int i = 0; i < SCAN_BLOCKS; ++i) { int v = s[i]; s[i] = run; run += v; }
        rp[N_NODES] = run;
    }
    if (t == 127) {            // independent of s[]; idle lane does bucket scan
        int run = 0;
        for (int i = 0; i < NBK; ++i) {
            int v = bcnt[i]; bbase[i] = run; bcur[i] = run; run += v;
        }
    }
    __syncthreads();
    if (t < SCAN_BLOCKS) boff[t] = s[t];
}

__global__ void __launch_bounds__(256)
scan_apply_kernel(const int* __restrict__ deg, const int* __restrict__ boff,
                  int* __restrict__ rp, int* __restrict__ cursor) {
    __shared__ int sc[256];
    int t = threadIdx.x;
    int gi = blockIdx.x * 256 + t;
    int4 v = make_int4(0, 0, 0, 0);
    if (gi < N4) v = ((const int4*)deg)[gi];
    int s = v.x + v.y + v.z + v.w;
    sc[t] = s;
    __syncthreads();
    for (int off = 1; off < 256; off <<= 1) {
        int val = sc[t];
        int add = (t >= off) ? sc[t - off] : 0;
        __syncthreads();
        sc[t] = val + add;
        __syncthreads();
    }
    if (gi < N4) {
        int prefix = boff[blockIdx.x] + ((t == 0) ? 0 : sc[t - 1]);
        int4 r;
        r.x = prefix;
        r.y = r.x + v.x;
        r.z = r.y + v.y;
        r.w = r.z + v.z;
        ((int4*)rp)[gi] = r;
        ((int4*)cursor)[gi] = r;
    }
}

// Block-level counting sort of 2048 edges into 16 dst-buckets; coalesced
// append to the partitioned edge buffer.
__global__ void __launch_bounds__(256)
part_kernel(const int* __restrict__ esrc, const int* __restrict__ edst,
            int* __restrict__ bcur, int2* __restrict__ ebuf) {
    __shared__ int cnt[NBK];
    __shared__ int lbase[NBK];
    __shared__ int gbase[NBK];
    __shared__ int2 stage[2048];          // 16 KB
    int t = threadIdx.x;
    if (t < NBK) cnt[t] = 0;
    __syncthreads();
    int base = blockIdx.x * 2048;
    int2 ed[8]; int bk[8]; int rk[8];
    #pragma unroll
    for (int k = 0; k < 8; ++k) {
        int e = base + k * 256 + t;
        if (e < N_EDGES) {
            ed[k].x = esrc[e];
            ed[k].y = edst[e];
            bk[k] = ed[k].y >> 13;
            rk[k] = atomicAdd(&cnt[bk[k]], 1);
        } else {
            bk[k] = -1; rk[k] = 0; ed[k] = make_int2(0, 0);
        }
    }
    __syncthreads();
    if (t == 0) {
        int run = 0;
        for (int i = 0; i < NBK; ++i) { lbase[i] = run; run += cnt[i]; }
    }
    __syncthreads();
    if (t < NBK) gbase[t] = cnt[t] ? atomicAdd(&bcur[t], cnt[t]) : 0;
    __syncthreads();
    #pragma unroll
    for (int k = 0; k < 8; ++k)
        if (bk[k] >= 0) stage[lbase[bk[k]] + rk[k]] = ed[k];
    __syncthreads();
    for (int b = 0; b < NBK; ++b) {
        int len = cnt[b], l0 = lbase[b], g0 = gbase[b];
        for (int i = t; i < len; i += 256) ebuf[g0 + i] = stage[l0 + i];
    }
}

// Per-bucket CSR fill: bucket = blockIdx&15 -> XCD blockIdx&7 (round-robin
// heuristic), confining cursor+ss writes to an L2-resident slice.
__global__ void __launch_bounds__(256)
fill2_kernel(const int2* __restrict__ ebuf, const int* __restrict__ bbase,
             const int* __restrict__ bcnt,
             int* __restrict__ cursor, int* __restrict__ ss) {
    int b = blockIdx.x & (NBK - 1);
    int chunk = blockIdx.x >> 4;          // 0..FILL2_CHUNKS-1
    int start = bbase[b];
    int n = bcnt[b];
    for (int i = chunk * 256 + threadIdx.x; i < n; i += FILL2_CHUNKS * 256) {
        int2 p = ebuf[start + i];
        int pos = atomicAdd(&cursor[p.y], 1);
        ss[pos] = p.x;
    }
}

// ---------------------------------------------------------------------------
// f32 -> bf16 conversion of input features
// ---------------------------------------------------------------------------
__global__ void __launch_bounds__(256)
conv_kernel(const float* __restrict__ x, ushort* __restrict__ xh) {
    int i = blockIdx.x * 256 + threadIdx.x;
    float4 v = ((const float4*)x)[i];
    ushort4 o;
    o.x = f2bf(v.x); o.y = f2bf(v.y); o.z = f2bf(v.z); o.w = f2bf(v.w);
    ((ushort4*)xh)[i] = o;
}

// ---------------------------------------------------------------------------
// Fused layer: CSR gather-mean (bf16 rows, pair-load) + concat + f32 GEMV.
// ---------------------------------------------------------------------------
__global__ void __launch_bounds__(512)
fused_sage_kernel(const ushort* __restrict__ xh,
                  const int* __restrict__ rp,
                  const int* __restrict__ ss,
                  const float* __restrict__ W,
                  const float* __restrict__ bias,
                  ushort* __restrict__ out_bf,
                  float* __restrict__ out_f)
{
    __shared__ float sW[2 * F * F];
    __shared__ float sb[F];
    __shared__ float sin_[8][2 * F];

    for (int i = threadIdx.x; i < 2 * F * F; i += 512) sW[i] = W[i];
    if (threadIdx.x < F) sb[threadIdx.x] = bias[threadIdx.x];

    const int w    = threadIdx.x >> 6;
    const int lane = threadIdx.x & 63;
    const int half = lane >> 5;
    const int p    = lane & 31;
    const int n    = blockIdx.x * 8 + w;

    const unsigned int* __restrict__ xw = (const unsigned int*)xh;

    if (n < N_NODES) {
        int start = rp[n];
        int end   = rp[n + 1];
        float ax = 0.0f, ay = 0.0f;

        int i = start;
        for (; i + 8 <= end; i += 8) {
            int e0 = i + half;
            int s0 = ss[e0], s1 = ss[e0 + 2], s2 = ss[e0 + 4], s3 = ss[e0 + 6];
            unsigned int u0 = xw[(size_t)s0 * 32 + p];
            unsigned int u1 = xw[(size_t)s1 * 32 + p];
            unsigned int u2 = xw[(size_t)s2 * 32 + p];
            unsigned int u3 = xw[(size_t)s3 * 32 + p];
            ax += bf2f((ushort)u0) + bf2f((ushort)u1)
                + bf2f((ushort)u2) + bf2f((ushort)u3);
            ay += bf2f((ushort)(u0 >> 16)) + bf2f((ushort)(u1 >> 16))
                + bf2f((ushort)(u2 >> 16)) + bf2f((ushort)(u3 >> 16));
        }
        for (; i + 2 <= end; i += 2) {
            int s0 = ss[i + half];
            unsigned int u0 = xw[(size_t)s0 * 32 + p];
            ax += bf2f((ushort)u0);
            ay += bf2f((ushort)(u0 >> 16));
        }
        if (i < end && half == 0) {
            int s0 = ss[i];
            unsigned int u0 = xw[(size_t)s0 * 32 + p];
            ax += bf2f((ushort)u0);
            ay += bf2f((ushort)(u0 >> 16));
        }
        ax += __shfl_xor(ax, 32);
        ay += __shfl_xor(ay, 32);

        float degf  = (float)(end - start);
        float scale = 1.0f / fmaxf(degf, 1.0f);
        if (half == 0) {
            sin_[w][F + 2 * p]     = ax * scale;
            sin_[w][F + 2 * p + 1] = ay * scale;
        }
        sin_[w][lane] = bf2f(xh[(size_t)n * F + lane]);
    }
    __syncthreads();

    if (n < N_NODES) {
        const int f = lane;
        float sum = sb[f];
        #pragma unroll
        for (int k = 0; k < 2 * F; ++k) {
            sum += sin_[w][k] * sW[k * F + f];
        }
        float r = fmaxf(sum, 0.0f);
        if (out_bf) out_bf[(size_t)n * F + f] = f2bf(r);
        if (out_f)  out_f[(size_t)n * F + f]  = r;
    }
}

extern "C" void kernel_launch(void* const* d_in, const int* in_sizes, int n_in,
                              void* d_out, int out_size, void* d_ws, size_t ws_size,
                              hipStream_t stream) {
    const float* x    = (const float*)d_in[0];
    const int*   esrc = (const int*)d_in[1];
    const int*   edst = (const int*)d_in[2];
    const float* W1   = (const float*)d_in[3];
    const float* b1   = (const float*)d_in[4];
    const float* W2   = (const float*)d_in[5];
    const float* b2   = (const float*)d_in[6];
    float* out = (float*)d_out;

    // Workspace layout (16B-aligned where vector-accessed):
    int*    deg    = (int*)d_ws;                       // 100000
    int*    bcnt   = deg + N_NODES;                    // 16
    int*    bbase  = bcnt + NBK;                       // 16
    int*    bcur   = bbase + NBK;                      // 16
    int*    cursor = bcur + NBK;                       // 100000 (16B-aligned)
    int*    rp     = cursor + N_NODES;                 // 100004 (16B-aligned)
    int*    ss     = rp + (N_NODES + 4);               // 1600000
    ushort* xh     = (ushort*)(ss + N_EDGES);          // 6.4M bf16 (12.8 MB)
    ushort* h1h    = xh + (size_t)N_NODES * F;         // 6.4M bf16 (12.8 MB)
    int2*   ebuf   = (int2*)h1h;                       // aliases h1h (pre-sage1)
    int*    bsum   = (int*)(h1h + (size_t)N_NODES * F);
    int*    boff   = bsum + 128;

    const int NB = (N_NODES + 7) / 8;            // 12500
    const int CB = (N_NODES * F / 4) / 256;      // 6250 (exact)

    hipMemsetAsync(deg, 0, ((size_t)N_NODES + NBK) * 4, stream);  // deg + bcnt
    bucket_hist_kernel<<<PART_BLOCKS, 256, 0, stream>>>(edst, deg, bcnt);
    partial_kernel<<<SCAN_BLOCKS, 256, 0, stream>>>(deg, bsum);
    scan_bsums_kernel<<<1, 128, 0, stream>>>(bsum, boff, rp, bcnt, bbase, bcur);
    scan_apply_kernel<<<SCAN_BLOCKS, 256, 0, stream>>>(deg, boff, rp, cursor);
    part_kernel<<<PART_BLOCKS, 256, 0, stream>>>(esrc, edst, bcur, ebuf);
    fill2_kernel<<<FILL2_BLOCKS, 256, 0, stream>>>(ebuf, bbase, bcnt, cursor, ss);
    conv_kernel<<<CB, 256, 0, stream>>>(x, xh);

    fused_sage_kernel<<<NB, 512, 0, stream>>>(xh,  rp, ss, W1, b1, h1h, nullptr);
    fused_sage_kernel<<<NB, 512, 0, stream>>>(h1h, rp, ss, W2, b2, nullptr, out);
}

// Round 9
// 410.787 us; speedup vs baseline: 2.5643x; 1.2114x over previous
//
#include <hip/hip_runtime.h>
#include <hip/hip_bf16.h>

// GraphSAGE forward, 2 layers. N=100000, E=1600000, F=64, W: [128,64].
//
// Round 9: round-8 profile: fused_sage = 2x133 us (53%). Model: GEMV phase
// costs ~42 us/layer of LDS pipe (128 ds_read_b32 of sW per node) + ~10 us
// fmac. Lever: MFMA-ize the GEMV. 32 nodes/block; gather packs concat input
// as bf16 into LDS cin[32][136]; GEMV = 32x mfma_f32_16x16x32_bf16 per block
// (A=cin, B=W^T bf16 staged in LDS via prep kernel). CSR build unchanged.

constexpr int N_NODES = 100000;
constexpr int N_EDGES = 1600000;
constexpr int F = 64;
constexpr int N4 = N_NODES / 4;               // 25000
constexpr int SCAN_BLOCKS = (N4 + 255) / 256; // 98
constexpr int NBK = 16;                       // buckets (dst >> 13)
constexpr int PART_BLOCKS = (N_EDGES + 2047) / 2048; // 782
constexpr int FILL2_CHUNKS = 48;
constexpr int FILL2_BLOCKS = NBK * FILL2_CHUNKS;     // 768
constexpr int LDW = 136;                      // padded bf16 row (272 B, 2-way banks)

typedef short short8 __attribute__((ext_vector_type(8)));
typedef float floatx4 __attribute__((ext_vector_type(4)));

// ---- bf16 helpers (RN-even; inputs are finite) ----
__device__ __forceinline__ float bf2f(ushort u) {
    union { unsigned int i; float f; } c; c.i = (unsigned int)u << 16; return c.f;
}
__device__ __forceinline__ ushort f2bf(float v) {
    union { float f; unsigned int i; } c; c.f = v;
    unsigned int r = c.i + 0x7fffu + ((c.i >> 16) & 1u);
    return (ushort)(r >> 16);
}

// ---------------------------------------------------------------------------
// CSR build (unchanged from round 8)
// ---------------------------------------------------------------------------

__global__ void __launch_bounds__(256)
bucket_hist_kernel(const int* __restrict__ edst, int* __restrict__ deg,
                   int* __restrict__ bcnt) {
    __shared__ int lb[NBK];
    int t = threadIdx.x;
    if (t < NBK) lb[t] = 0;
    __syncthreads();
    int base = blockIdx.x * 2048;
    #pragma unroll
    for (int k = 0; k < 8; ++k) {
        int e = base + k * 256 + t;
        if (e < N_EDGES) {
            int d = edst[e];
            atomicAdd(&deg[d], 1);
            atomicAdd(&lb[d >> 13], 1);
        }
    }
    __syncthreads();
    if (t < NBK && lb[t]) atomicAdd(&bcnt[t], lb[t]);
}

__global__ void __launch_bounds__(256)
partial_kernel(const int* __restrict__ deg, int* __restrict__ bsum) {
    __shared__ int red[256];
    int t = threadIdx.x;
    int gi = blockIdx.x * 256 + t;
    int s = 0;
    if (gi < N4) {
        int4 v = ((const int4*)deg)[gi];
        s = v.x + v.y + v.z + v.w;
    }
    red[t] = s;
    __syncthreads();
    for (int off = 128; off > 0; off >>= 1) {
        if (t < off) red[t] += red[t + off];
        __syncthreads();
    }
    if (t == 0) bsum[blockIdx.x] = red[0];
}

__global__ void __launch_bounds__(128)
scan_bsums_kernel(const int* __restrict__ bsum, int* __restrict__ boff,
                  int* __restrict__ rp,
                  const int* __restrict__ bcnt, int* __restrict__ bbase,
                  int* __restrict__ bcur) {
    __shared__ int s[SCAN_BLOCKS];
    int t = threadIdx.x;
    if (t < SCAN_BLOCKS) s[t] = bsum[t];
    __syncthreads();
    if (t == 0) {
        int run = 0;
        for (int i = 0; i < SCAN_BLOCKS; ++i) { int v = s[i]; s[i] = run; run += v; }
        rp[N_NODES] = run;
    }
    if (t == 127) {
        int run = 0;
        for (int i = 0; i < NBK; ++i) {
            int v = bcnt[i]; bbase[i] = run; bcur[i] = run; run += v;
        }
    }
    __syncthreads();
    if (t < SCAN_BLOCKS) boff[t] = s[t];
}

__global__ void __launch_bounds__(256)
scan_apply_kernel(const int* __restrict__ deg, const int* __restrict__ boff,
                  int* __restrict__ rp, int* __restrict__ cursor) {
    __shared__ int sc[256];
    int t = threadIdx.x;
    int gi = blockIdx.x * 256 + t;
    int4 v = make_int4(0, 0, 0, 0);
    if (gi < N4) v = ((const int4*)deg)[gi];
    int s = v.x + v.y + v.z + v.w;
    sc[t] = s;
    __syncthreads();
    for (int off = 1; off < 256; off <<= 1) {
        int val = sc[t];
        int add = (t >= off) ? sc[t - off] : 0;
        __syncthreads();
        sc[t] = val + add;
        __syncthreads();
    }
    if (gi < N4) {
        int prefix = boff[blockIdx.x] + ((t == 0) ? 0 : sc[t - 1]);
        int4 r;
        r.x = prefix;
        r.y = r.x + v.x;
        r.z = r.y + v.y;
        r.w = r.z + v.z;
        ((int4*)rp)[gi] = r;
        ((int4*)cursor)[gi] = r;
    }
}

__global__ void __launch_bounds__(256)
part_kernel(const int* __restrict__ esrc, const int* __restrict__ edst,
            int* __restrict__ bcur, int2* __restrict__ ebuf) {
    __shared__ int cnt[NBK];
    __shared__ int lbase[NBK];
    __shared__ int gbase[NBK];
    __shared__ int2 stage[2048];
    int t = threadIdx.x;
    if (t < NBK) cnt[t] = 0;
    __syncthreads();
    int base = blockIdx.x * 2048;
    int2 ed[8]; int bk[8]; int rk[8];
    #pragma unroll
    for (int k = 0; k < 8; ++k) {
        int e = base + k * 256 + t;
        if (e < N_EDGES) {
            ed[k].x = esrc[e];
            ed[k].y = edst[e];
            bk[k] = ed[k].y >> 13;
            rk[k] = atomicAdd(&cnt[bk[k]], 1);
        } else {
            bk[k] = -1; rk[k] = 0; ed[k] = make_int2(0, 0);
        }
    }
    __syncthreads();
    if (t == 0) {
        int run = 0;
        for (int i = 0; i < NBK; ++i) { lbase[i] = run; run += cnt[i]; }
    }
    __syncthreads();
    if (t < NBK) gbase[t] = cnt[t] ? atomicAdd(&bcur[t], cnt[t]) : 0;
    __syncthreads();
    #pragma unroll
    for (int k = 0; k < 8; ++k)
        if (bk[k] >= 0) stage[lbase[bk[k]] + rk[k]] = ed[k];
    __syncthreads();
    for (int b = 0; b < NBK; ++b) {
        int len = cnt[b], l0 = lbase[b], g0 = gbase[b];
        for (int i = t; i < len; i += 256) ebuf[g0 + i] = stage[l0 + i];
    }
}

__global__ void __launch_bounds__(256)
fill2_kernel(const int2* __restrict__ ebuf, const int* __restrict__ bbase,
             const int* __restrict__ bcnt,
             int* __restrict__ cursor, int* __restrict__ ss) {
    int b = blockIdx.x & (NBK - 1);
    int chunk = blockIdx.x >> 4;
    int start = bbase[b];
    int n = bcnt[b];
    for (int i = chunk * 256 + threadIdx.x; i < n; i += FILL2_CHUNKS * 256) {
        int2 p = ebuf[start + i];
        int pos = atomicAdd(&cursor[p.y], 1);
        ss[pos] = p.x;
    }
}

// ---------------------------------------------------------------------------
// f32 -> bf16 conversion of input features
// ---------------------------------------------------------------------------
__global__ void __launch_bounds__(256)
conv_kernel(const float* __restrict__ x, ushort* __restrict__ xh) {
    int i = blockIdx.x * 256 + threadIdx.x;
    float4 v = ((const float4*)x)[i];
    ushort4 o;
    o.x = f2bf(v.x); o.y = f2bf(v.y); o.z = f2bf(v.z); o.w = f2bf(v.w);
    ((ushort4*)xh)[i] = o;
}

// W[128][64] f32 -> Wt[64][LDW] bf16 (transposed, padded). One block.
__global__ void __launch_bounds__(512)
prep_w_kernel(const float* __restrict__ W, ushort* __restrict__ Wt) {
    for (int i = threadIdx.x; i < 2 * F * F; i += 512) {
        int k = i >> 6, f = i & 63;
        Wt[f * LDW + k] = f2bf(W[i]);
    }
}

// ---------------------------------------------------------------------------
// Fused layer: CSR gather-mean (bf16 pair-load) -> LDS cin (bf16) -> MFMA
// GEMV (A = cin[32][128], B = Wt^T) + bias + ReLU.
// Block = 512 = 8 waves; 32 nodes/block (4 per wave in gather phase).
// MFMA tiles: Mt = wave>>2 (2), Nt = wave&3 (4), K-loop 4 x 32.
// ---------------------------------------------------------------------------
__global__ void __launch_bounds__(512)
fused_sage_kernel(const ushort* __restrict__ xh,
                  const int* __restrict__ rp,
                  const int* __restrict__ ss,
                  const ushort* __restrict__ Wt,   // [64][LDW] bf16
                  const float* __restrict__ bias,
                  ushort* __restrict__ out_bf,
                  float* __restrict__ out_f)
{
    __shared__ ushort sWt[F * LDW];      // 17408 B
    __shared__ ushort cin[32 * LDW];     // 8704 B

    // stage Wt as dwords (F*LDW/2 = 4352 dwords), coalesced
    {
        const int* src = (const int*)Wt;
        int* dst = (int*)sWt;
        for (int i = threadIdx.x; i < F * LDW / 2; i += 512) dst[i] = src[i];
    }

    const int w    = threadIdx.x >> 6;
    const int lane = threadIdx.x & 63;
    const int half = lane >> 5;
    const int p    = lane & 31;

    const unsigned int* __restrict__ xw = (const unsigned int*)xh;

    // ---- gather phase: 4 nodes per wave ----
    for (int q = 0; q < 4; ++q) {
        const int n = blockIdx.x * 32 + w * 4 + q;   // grid exact: 3125*32=100000
        int start = rp[n];
        int end   = rp[n + 1];
        float ax = 0.0f, ay = 0.0f;

        int i = start;
        for (; i + 8 <= end; i += 8) {
            int e0 = i + half;
            int s0 = ss[e0], s1 = ss[e0 + 2], s2 = ss[e0 + 4], s3 = ss[e0 + 6];
            unsigned int u0 = xw[(size_t)s0 * 32 + p];
            unsigned int u1 = xw[(size_t)s1 * 32 + p];
            unsigned int u2 = xw[(size_t)s2 * 32 + p];
            unsigned int u3 = xw[(size_t)s3 * 32 + p];
            ax += bf2f((ushort)u0) + bf2f((ushort)u1)
                + bf2f((ushort)u2) + bf2f((ushort)u3);
            ay += bf2f((ushort)(u0 >> 16)) + bf2f((ushort)(u1 >> 16))
                + bf2f((ushort)(u2 >> 16)) + bf2f((ushort)(u3 >> 16));
        }
        for (; i + 2 <= end; i += 2) {
            int s0 = ss[i + half];
            unsigned int u0 = xw[(size_t)s0 * 32 + p];
            ax += bf2f((ushort)u0);
            ay += bf2f((ushort)(u0 >> 16));
        }
        if (i < end && half == 0) {
            int s0 = ss[i];
            unsigned int u0 = xw[(size_t)s0 * 32 + p];
            ax += bf2f((ushort)u0);
            ay += bf2f((ushort)(u0 >> 16));
        }
        ax += __shfl_xor(ax, 32);
        ay += __shfl_xor(ay, 32);

        if (half == 0) {
            unsigned int* crow = (unsigned int*)&cin[(w * 4 + q) * LDW];
            crow[p] = xw[(size_t)n * 32 + p];              // self feats 2p,2p+1
            float scale = 1.0f / fmaxf((float)(end - start), 1.0f);
            unsigned int lo = f2bf(ax * scale);
            unsigned int hi = f2bf(ay * scale);
            crow[32 + p] = (hi << 16) | lo;                // mean feats
        }
    }
    __syncthreads();

    // ---- MFMA GEMV: C[32x64] = cin[32x128] @ W[128x64] ----
    const int Mt = w >> 2, Nt = w & 3;
    const int r16 = lane & 15, g4 = lane >> 4;
    floatx4 acc = {0.0f, 0.0f, 0.0f, 0.0f};
    #pragma unroll
    for (int ks = 0; ks < 4; ++ks) {
        short8 a = *(const short8*)&cin[(Mt * 16 + r16) * LDW + ks * 32 + g4 * 8];
        short8 b = *(const short8*)&sWt[(Nt * 16 + r16) * LDW + ks * 32 + g4 * 8];
        acc = __builtin_amdgcn_mfma_f32_16x16x32_bf16(a, b, acc, 0, 0, 0);
    }
    const int feat = Nt * 16 + r16;
    const float bv = bias[feat];
    #pragma unroll
    for (int reg = 0; reg < 4; ++reg) {
        int node = blockIdx.x * 32 + Mt * 16 + g4 * 4 + reg;
        float r = fmaxf(acc[reg] + bv, 0.0f);
        if (out_bf) out_bf[(size_t)node * F + feat] = f2bf(r);
        if (out_f)  out_f [(size_t)node * F + feat] = r;
    }
}

extern "C" void kernel_launch(void* const* d_in, const int* in_sizes, int n_in,
                              void* d_out, int out_size, void* d_ws, size_t ws_size,
                              hipStream_t stream) {
    const float* x    = (const float*)d_in[0];
    const int*   esrc = (const int*)d_in[1];
    const int*   edst = (const int*)d_in[2];
    const float* W1   = (const float*)d_in[3];
    const float* b1   = (const float*)d_in[4];
    const float* W2   = (const float*)d_in[5];
    const float* b2   = (const float*)d_in[6];
    float* out = (float*)d_out;

    // Workspace layout:
    int*    deg    = (int*)d_ws;                       // 100000
    int*    bcnt   = deg + N_NODES;                    // 16
    int*    bbase  = bcnt + NBK;                       // 16
    int*    bcur   = bbase + NBK;                      // 16
    int*    cursor = bcur + NBK;                       // 100000
    int*    rp     = cursor + N_NODES;                 // 100004
    int*    ss     = rp + (N_NODES + 4);               // 1600000
    ushort* xh     = (ushort*)(ss + N_EDGES);          // 6.4M bf16 (12.8 MB)
    ushort* h1h    = xh + (size_t)N_NODES * F;         // 6.4M bf16 (12.8 MB)
    int2*   ebuf   = (int2*)h1h;                       // aliases h1h (pre-sage1)
    int*    bsum   = (int*)(h1h + (size_t)N_NODES * F);
    int*    boff   = bsum + 128;                       // 128
    ushort* Wt1g   = (ushort*)(boff + 128);            // 64*LDW bf16
    ushort* Wt2g   = Wt1g + F * LDW;                   // 64*LDW bf16

    const int NB = N_NODES / 32;                 // 3125 (exact)
    const int CB = (N_NODES * F / 4) / 256;      // 6250 (exact)

    hipMemsetAsync(deg, 0, ((size_t)N_NODES + NBK) * 4, stream);
    bucket_hist_kernel<<<PART_BLOCKS, 256, 0, stream>>>(edst, deg, bcnt);
    partial_kernel<<<SCAN_BLOCKS, 256, 0, stream>>>(deg, bsum);
    scan_bsums_kernel<<<1, 128, 0, stream>>>(bsum, boff, rp, bcnt, bbase, bcur);
    scan_apply_kernel<<<SCAN_BLOCKS, 256, 0, stream>>>(deg, boff, rp, cursor);
    part_kernel<<<PART_BLOCKS, 256, 0, stream>>>(esrc, edst, bcur, ebuf);
    fill2_kernel<<<FILL2_BLOCKS, 256, 0, stream>>>(ebuf, bbase, bcnt, cursor, ss);
    conv_kernel<<<CB, 256, 0, stream>>>(x, xh);
    prep_w_kernel<<<1, 512, 0, stream>>>(W1, Wt1g);
    prep_w_kernel<<<1, 512, 0, stream>>>(W2, Wt2g);

    fused_sage_kernel<<<NB, 512, 0, stream>>>(xh,  rp, ss, Wt1g, b1, h1h, nullptr);
    fused_sage_kernel<<<NB, 512, 0, stream>>>(h1h, rp, ss, Wt2g, b2, nullptr, out);
}

// Round 10
// 327.695 us; speedup vs baseline: 3.2145x; 1.2536x over previous
//
#include <hip/hip_runtime.h>
#include <hip/hip_bf16.h>

// GraphSAGE forward, 2 layers. N=100000, E=1600000, F=64, W: [128,64].
//
// Round 10: round-9: fused_sage 2x74 us; CSR build = ~260 us (64%) across 9
// sub-top-5 dispatches. Lever: atomic-free bucket-local CSR build.
// 64 buckets (dst>>11). count (LDS) -> scan64 -> part (counting sort to
// partitioned ebuf) -> csr_bucket (per-bucket LDS deg hist + block scan +
// LDS-cursor fill => rp, ss). No per-edge global atomics anywhere.
// fused_sage (MFMA GEMV) unchanged from round 9.

constexpr int N_NODES = 100000;
constexpr int N_EDGES = 1600000;
constexpr int F = 64;
constexpr int NBK = 64;                        // buckets, span 2048 (dst>>11)
constexpr int NBK_USED = (N_NODES + 2047) / 2048;  // 49
constexpr int PART_T = 512;
constexpr int PART_E = 4096;
constexpr int PART_BLOCKS = (N_EDGES + PART_E - 1) / PART_E;   // 391
constexpr int COUNT_BLOCKS = (N_EDGES + 2047) / 2048;          // 782
constexpr int LDW = 136;                       // padded bf16 row

typedef short short8 __attribute__((ext_vector_type(8)));
typedef float floatx4 __attribute__((ext_vector_type(4)));

// ---- bf16 helpers (RN-even; inputs are finite) ----
__device__ __forceinline__ float bf2f(ushort u) {
    union { unsigned int i; float f; } c; c.i = (unsigned int)u << 16; return c.f;
}
__device__ __forceinline__ ushort f2bf(float v) {
    union { float f; unsigned int i; } c; c.f = v;
    unsigned int r = c.i + 0x7fffu + ((c.i >> 16) & 1u);
    return (ushort)(r >> 16);
}

// ---------------------------------------------------------------------------
// CSR build, bucket-local
// ---------------------------------------------------------------------------

__global__ void __launch_bounds__(256)
count_kernel(const int* __restrict__ edst, int* __restrict__ bcnt) {
    __shared__ int lb[NBK];
    int t = threadIdx.x;
    if (t < NBK) lb[t] = 0;
    __syncthreads();
    int base = blockIdx.x * 2048;
    #pragma unroll
    for (int k = 0; k < 8; ++k) {
        int e = base + k * 256 + t;
        if (e < N_EDGES) atomicAdd(&lb[edst[e] >> 11], 1);
    }
    __syncthreads();
    if (t < NBK && lb[t]) atomicAdd(&bcnt[t], lb[t]);
}

__global__ void __launch_bounds__(64)
scan_b64_kernel(const int* __restrict__ bcnt, int* __restrict__ bbase,
                int* __restrict__ bcur, int* __restrict__ rp) {
    if (threadIdx.x == 0) {
        int run = 0;
        for (int i = 0; i < NBK; ++i) {
            bbase[i] = run; bcur[i] = run; run += bcnt[i];
        }
        rp[N_NODES] = run;   // = E
    }
}

// Block-level counting sort of 4096 edges into 64 dst-buckets; coalesced
// append (avg 64-edge runs) into the partitioned edge buffer.
__global__ void __launch_bounds__(PART_T)
part_kernel(const int* __restrict__ esrc, const int* __restrict__ edst,
            int* __restrict__ bcur, int2* __restrict__ ebuf) {
    __shared__ int cnt[NBK];
    __shared__ int lbase[NBK];
    __shared__ int gbase[NBK];
    __shared__ int2 stage[PART_E];        // 32 KB
    int t = threadIdx.x;
    if (t < NBK) cnt[t] = 0;
    __syncthreads();
    int base = blockIdx.x * PART_E;
    int2 ed[8]; int bk[8]; int rk[8];
    #pragma unroll
    for (int k = 0; k < 8; ++k) {
        int e = base + k * PART_T + t;
        if (e < N_EDGES) {
            ed[k].x = esrc[e];
            ed[k].y = edst[e];
            bk[k] = ed[k].y >> 11;
            rk[k] = atomicAdd(&cnt[bk[k]], 1);
        } else {
            bk[k] = -1; rk[k] = 0; ed[k] = make_int2(0, 0);
        }
    }
    __syncthreads();
    if (t == 0) {
        int run = 0;
        for (int i = 0; i < NBK; ++i) { lbase[i] = run; run += cnt[i]; }
    }
    __syncthreads();
    if (t < NBK) gbase[t] = cnt[t] ? atomicAdd(&bcur[t], cnt[t]) : 0;
    __syncthreads();
    #pragma unroll
    for (int k = 0; k < 8; ++k)
        if (bk[k] >= 0) stage[lbase[bk[k]] + rk[k]] = ed[k];
    __syncthreads();
    for (int b = 0; b < NBK; ++b) {
        int len = cnt[b], l0 = lbase[b], g0 = gbase[b];
        for (int i = t; i < len; i += PART_T) ebuf[g0 + i] = stage[l0 + i];
    }
}

// One block per bucket: LDS deg hist over the bucket's 2048 nodes, block
// exclusive scan -> rp slice, LDS-cursor fill -> ss slice. No global atomics.
__global__ void __launch_bounds__(1024)
csr_bucket_kernel(const int2* __restrict__ ebuf, const int* __restrict__ bbase,
                  const int* __restrict__ bcnt,
                  int* __restrict__ rp, int* __restrict__ ss) {
    __shared__ int sdeg[2048];
    __shared__ int spart[1024];
    int b = blockIdx.x;
    int lo = b << 11;
    int nn = N_NODES - lo; if (nn > 2048) nn = 2048;
    int bstart = bbase[b];
    int bn = bcnt[b];
    int t = threadIdx.x;

    sdeg[t] = 0; sdeg[t + 1024] = 0;
    __syncthreads();
    for (int i = t; i < bn; i += 1024)
        atomicAdd(&sdeg[ebuf[bstart + i].y - lo], 1);
    __syncthreads();

    int a0 = sdeg[2 * t], a1 = sdeg[2 * t + 1];
    spart[t] = a0 + a1;
    __syncthreads();
    for (int off = 1; off < 1024; off <<= 1) {
        int v = spart[t];
        int add = (t >= off) ? spart[t - off] : 0;
        __syncthreads();
        spart[t] = v + add;
        __syncthreads();
    }
    int ex = (t == 0) ? 0 : spart[t - 1];
    sdeg[2 * t]     = ex;        // local cursors (exclusive scan)
    sdeg[2 * t + 1] = ex + a0;
    if (2 * t < nn)     rp[lo + 2 * t]     = bstart + ex;
    if (2 * t + 1 < nn) rp[lo + 2 * t + 1] = bstart + ex + a0;
    __syncthreads();

    for (int i = t; i < bn; i += 1024) {
        int2 p = ebuf[bstart + i];
        int pos = atomicAdd(&sdeg[p.y - lo], 1);   // LDS atomic
        ss[bstart + pos] = p.x;
    }
}

// ---------------------------------------------------------------------------
// f32 -> bf16 conversion of input features
// ---------------------------------------------------------------------------
__global__ void __launch_bounds__(256)
conv_kernel(const float* __restrict__ x, ushort* __restrict__ xh) {
    int i = blockIdx.x * 256 + threadIdx.x;
    float4 v = ((const float4*)x)[i];
    ushort4 o;
    o.x = f2bf(v.x); o.y = f2bf(v.y); o.z = f2bf(v.z); o.w = f2bf(v.w);
    ((ushort4*)xh)[i] = o;
}

// Both W's: W[128][64] f32 -> Wt[64][LDW] bf16 (transposed, padded). Grid=2.
__global__ void __launch_bounds__(512)
prep_w_kernel(const float* __restrict__ W1, const float* __restrict__ W2,
              ushort* __restrict__ Wt1, ushort* __restrict__ Wt2) {
    const float* W = blockIdx.x ? W2 : W1;
    ushort* Wt = blockIdx.x ? Wt2 : Wt1;
    for (int i = threadIdx.x; i < 2 * F * F; i += 512) {
        int k = i >> 6, f = i & 63;
        Wt[f * LDW + k] = f2bf(W[i]);
    }
}

// ---------------------------------------------------------------------------
// Fused layer (unchanged from round 9): CSR gather-mean (bf16 pair-load) ->
// LDS cin (bf16) -> MFMA GEMV + bias + ReLU. 512 thr = 8 waves, 32 nodes/blk.
// ---------------------------------------------------------------------------
__global__ void __launch_bounds__(512)
fused_sage_kernel(const ushort* __restrict__ xh,
                  const int* __restrict__ rp,
                  const int* __restrict__ ss,
                  const ushort* __restrict__ Wt,   // [64][LDW] bf16
                  const float* __restrict__ bias,
                  ushort* __restrict__ out_bf,
                  float* __restrict__ out_f)
{
    __shared__ ushort sWt[F * LDW];
    __shared__ ushort cin[32 * LDW];

    {
        const int* src = (const int*)Wt;
        int* dst = (int*)sWt;
        for (int i = threadIdx.x; i < F * LDW / 2; i += 512) dst[i] = src[i];
    }

    const int w    = threadIdx.x >> 6;
    const int lane = threadIdx.x & 63;
    const int half = lane >> 5;
    const int p    = lane & 31;

    const unsigned int* __restrict__ xw = (const unsigned int*)xh;

    for (int q = 0; q < 4; ++q) {
        const int n = blockIdx.x * 32 + w * 4 + q;
        int start = rp[n];
        int end   = rp[n + 1];
        float ax = 0.0f, ay = 0.0f;

        int i = start;
        for (; i + 8 <= end; i += 8) {
            int e0 = i + half;
            int s0 = ss[e0], s1 = ss[e0 + 2], s2 = ss[e0 + 4], s3 = ss[e0 + 6];
            unsigned int u0 = xw[(size_t)s0 * 32 + p];
            unsigned int u1 = xw[(size_t)s1 * 32 + p];
            unsigned int u2 = xw[(size_t)s2 * 32 + p];
            unsigned int u3 = xw[(size_t)s3 * 32 + p];
            ax += bf2f((ushort)u0) + bf2f((ushort)u1)
                + bf2f((ushort)u2) + bf2f((ushort)u3);
            ay += bf2f((ushort)(u0 >> 16)) + bf2f((ushort)(u1 >> 16))
                + bf2f((ushort)(u2 >> 16)) + bf2f((ushort)(u3 >> 16));
        }
        for (; i + 2 <= end; i += 2) {
            int s0 = ss[i + half];
            unsigned int u0 = xw[(size_t)s0 * 32 + p];
            ax += bf2f((ushort)u0);
            ay += bf2f((ushort)(u0 >> 16));
        }
        if (i < end && half == 0) {
            int s0 = ss[i];
            unsigned int u0 = xw[(size_t)s0 * 32 + p];
            ax += bf2f((ushort)u0);
            ay += bf2f((ushort)(u0 >> 16));
        }
        ax += __shfl_xor(ax, 32);
        ay += __shfl_xor(ay, 32);

        if (half == 0) {
            unsigned int* crow = (unsigned int*)&cin[(w * 4 + q) * LDW];
            crow[p] = xw[(size_t)n * 32 + p];
            float scale = 1.0f / fmaxf((float)(end - start), 1.0f);
            unsigned int lo = f2bf(ax * scale);
            unsigned int hi = f2bf(ay * scale);
            crow[32 + p] = (hi << 16) | lo;
        }
    }
    __syncthreads();

    const int Mt = w >> 2, Nt = w & 3;
    const int r16 = lane & 15, g4 = lane >> 4;
    floatx4 acc = {0.0f, 0.0f, 0.0f, 0.0f};
    #pragma unroll
    for (int ks = 0; ks < 4; ++ks) {
        short8 a = *(const short8*)&cin[(Mt * 16 + r16) * LDW + ks * 32 + g4 * 8];
        short8 b = *(const short8*)&sWt[(Nt * 16 + r16) * LDW + ks * 32 + g4 * 8];
        acc = __builtin_amdgcn_mfma_f32_16x16x32_bf16(a, b, acc, 0, 0, 0);
    }
    const int feat = Nt * 16 + r16;
    const float bv = bias[feat];
    #pragma unroll
    for (int reg = 0; reg < 4; ++reg) {
        int node = blockIdx.x * 32 + Mt * 16 + g4 * 4 + reg;
        float r = fmaxf(acc[reg] + bv, 0.0f);
        if (out_bf) out_bf[(size_t)node * F + feat] = f2bf(r);
        if (out_f)  out_f [(size_t)node * F + feat] = r;
    }
}

extern "C" void kernel_launch(void* const* d_in, const int* in_sizes, int n_in,
                              void* d_out, int out_size, void* d_ws, size_t ws_size,
                              hipStream_t stream) {
    const float* x    = (const float*)d_in[0];
    const int*   esrc = (const int*)d_in[1];
    const int*   edst = (const int*)d_in[2];
    const float* W1   = (const float*)d_in[3];
    const float* b1   = (const float*)d_in[4];
    const float* W2   = (const float*)d_in[5];
    const float* b2   = (const float*)d_in[6];
    float* out = (float*)d_out;

    // Workspace layout (16B-aligned blocks):
    int*    bcnt   = (int*)d_ws;                       // 64
    int*    bbase  = bcnt + NBK;                       // 64
    int*    bcur   = bbase + NBK;                      // 64
    int*    rp     = bcur + NBK + 64;                  // 100004 (+pad)
    int*    ss     = rp + (N_NODES + 12);              // 1600000
    ushort* xh     = (ushort*)(ss + N_EDGES);          // 6.4M bf16 (12.8 MB)
    ushort* h1h    = xh + (size_t)N_NODES * F;         // 6.4M bf16 (12.8 MB)
    int2*   ebuf   = (int2*)h1h;                       // aliases h1h (pre-sage1)
    ushort* Wt1g   = h1h + (size_t)N_NODES * F;        // 64*LDW bf16
    ushort* Wt2g   = Wt1g + F * LDW;                   // 64*LDW bf16

    const int NB = N_NODES / 32;                 // 3125 (exact)
    const int CB = (N_NODES * F / 4) / 256;      // 6250 (exact)

    hipMemsetAsync(bcnt, 0, NBK * 4, stream);
    count_kernel<<<COUNT_BLOCKS, 256, 0, stream>>>(edst, bcnt);
    scan_b64_kernel<<<1, 64, 0, stream>>>(bcnt, bbase, bcur, rp);
    part_kernel<<<PART_BLOCKS, PART_T, 0, stream>>>(esrc, edst, bcur, ebuf);
    csr_bucket_kernel<<<NBK_USED, 1024, 0, stream>>>(ebuf, bbase, bcnt, rp, ss);
    conv_kernel<<<CB, 256, 0, stream>>>(x, xh);
    prep_w_kernel<<<2, 512, 0, stream>>>(W1, W2, Wt1g, Wt2g);

    fused_sage_kernel<<<NB, 512, 0, stream>>>(xh,  rp, ss, Wt1g, b1, h1h, nullptr);
    fused_sage_kernel<<<NB, 512, 0, stream>>>(h1h, rp, ss, Wt2g, b2, nullptr, out);
}

// Round 11
// 303.464 us; speedup vs baseline: 3.4712x; 1.0798x over previous
//
#include <hip/hip_runtime.h>
#include <hip/hip_bf16.h>

// GraphSAGE forward, 2 layers. N=100000, E=1600000, F=64, W: [128,64].
//
// Round 11: round-10: fused_sage 2x74 us; build ~180 us, structure-bound:
// csr_bucket had only 49 blocks, part_kernel's tail was serial over 64
// buckets. Lever: bucket span 2048 -> 512 (dst>>9, 196 buckets) so
// csr_bucket = 196 blocks x 512 thr; part tail = wave-parallel (8 waves x
// 32 buckets); scan+prep_w fused. fused_sage (MFMA GEMV) unchanged.

constexpr int N_NODES = 100000;
constexpr int N_EDGES = 1600000;
constexpr int F = 64;
constexpr int SH = 9;                          // bucket shift (span 512)
constexpr int SPAN = 1 << SH;                  // 512
constexpr int NBK = 256;                       // bucket array size
constexpr int NBK_USED = (N_NODES + SPAN - 1) / SPAN;  // 196
constexpr int PART_T = 512;
constexpr int PART_E = 4096;
constexpr int PART_BLOCKS = (N_EDGES + PART_E - 1) / PART_E;   // 391
constexpr int COUNT_BLOCKS = (N_EDGES + 2047) / 2048;          // 782
constexpr int LDW = 136;                       // padded bf16 row

typedef short short8 __attribute__((ext_vector_type(8)));
typedef float floatx4 __attribute__((ext_vector_type(4)));

// ---- bf16 helpers (RN-even; inputs are finite) ----
__device__ __forceinline__ float bf2f(ushort u) {
    union { unsigned int i; float f; } c; c.i = (unsigned int)u << 16; return c.f;
}
__device__ __forceinline__ ushort f2bf(float v) {
    union { float f; unsigned int i; } c; c.f = v;
    unsigned int r = c.i + 0x7fffu + ((c.i >> 16) & 1u);
    return (ushort)(r >> 16);
}

// ---------------------------------------------------------------------------
// CSR build, bucket-local (256 buckets of 512 nodes)
// ---------------------------------------------------------------------------

__global__ void __launch_bounds__(256)
count_kernel(const int* __restrict__ edst, int* __restrict__ bcnt) {
    __shared__ int lb[NBK];
    int t = threadIdx.x;
    lb[t] = 0;
    __syncthreads();
    int base = blockIdx.x * 2048;
    #pragma unroll
    for (int k = 0; k < 8; ++k) {
        int e = base + k * 256 + t;
        if (e < N_EDGES) atomicAdd(&lb[edst[e] >> SH], 1);
    }
    __syncthreads();
    if (lb[t]) atomicAdd(&bcnt[t], lb[t]);
}

// Bucket scan (1 thread over LDS) + W1/W2 transpose-convert. One block.
__global__ void __launch_bounds__(512)
scan_prep_kernel(const int* __restrict__ bcnt, int* __restrict__ bbase,
                 int* __restrict__ bcur, int* __restrict__ rp,
                 const float* __restrict__ W1, const float* __restrict__ W2,
                 ushort* __restrict__ Wt1, ushort* __restrict__ Wt2) {
    __shared__ int sb[NBK];
    int t = threadIdx.x;
    if (t < NBK) sb[t] = bcnt[t];
    __syncthreads();
    if (t == 0) {
        int run = 0;
        for (int i = 0; i < NBK; ++i) { int v = sb[i]; sb[i] = run; run += v; }
        rp[N_NODES] = run;   // = E
    }
    __syncthreads();
    if (t < NBK) { bbase[t] = sb[t]; bcur[t] = sb[t]; }
    for (int i = t; i < 2 * F * F; i += 512) {
        int k = i >> 6, f = i & 63;
        Wt1[f * LDW + k] = f2bf(W1[i]);
        Wt2[f * LDW + k] = f2bf(W2[i]);
    }
}

// Block-level counting sort of 4096 edges into 256 dst-buckets; wave-parallel
// coalesced append into the partitioned edge buffer.
__global__ void __launch_bounds__(PART_T)
part_kernel(const int* __restrict__ esrc, const int* __restrict__ edst,
            int* __restrict__ bcur, int2* __restrict__ ebuf) {
    __shared__ int cnt[NBK];
    __shared__ int lbase[NBK];
    __shared__ int gbase[NBK];
    __shared__ int2 stage[PART_E];        // 32 KB
    int t = threadIdx.x;
    if (t < NBK) cnt[t] = 0;
    __syncthreads();
    int base = blockIdx.x * PART_E;
    int2 ed[8]; int bk[8]; int rk[8];
    #pragma unroll
    for (int k = 0; k < 8; ++k) {
        int e = base + k * PART_T + t;
        if (e < N_EDGES) {
            ed[k].x = esrc[e];
            ed[k].y = edst[e];
            bk[k] = ed[k].y >> SH;
            rk[k] = atomicAdd(&cnt[bk[k]], 1);
        } else {
            bk[k] = -1; rk[k] = 0; ed[k] = make_int2(0, 0);
        }
    }
    __syncthreads();
    // parallel exclusive scan of cnt[256] (Hillis-Steele on 256 lanes)
    {
        int v = 0;
        if (t < NBK) { v = cnt[t]; lbase[t] = v; }
        __syncthreads();
        for (int off = 1; off < NBK; off <<= 1) {
            int add = 0;
            if (t < NBK && t >= off) add = lbase[t - off];
            __syncthreads();
            if (t < NBK) lbase[t] += add;
            __syncthreads();
        }
        if (t < NBK) lbase[t] -= v;            // inclusive -> exclusive
    }
    __syncthreads();
    if (t < NBK) gbase[t] = cnt[t] ? atomicAdd(&bcur[t], cnt[t]) : 0;
    __syncthreads();
    #pragma unroll
    for (int k = 0; k < 8; ++k)
        if (bk[k] >= 0) stage[lbase[bk[k]] + rk[k]] = ed[k];
    __syncthreads();
    // wave-parallel output: wave w copies buckets w*32 .. w*32+31
    {
        int w = t >> 6, lane = t & 63;
        for (int b = w * 32; b < w * 32 + 32; ++b) {
            int len = cnt[b], l0 = lbase[b], g0 = gbase[b];
            for (int i = lane; i < len; i += 64) ebuf[g0 + i] = stage[l0 + i];
        }
    }
}

// One block per bucket (196 blocks, 512 thr): LDS deg hist over 512 nodes,
// exclusive scan -> rp slice, LDS-cursor fill -> ss slice. No global atomics.
__global__ void __launch_bounds__(512)
csr_bucket_kernel(const int2* __restrict__ ebuf, const int* __restrict__ bbase,
                  const int* __restrict__ bcnt,
                  int* __restrict__ rp, int* __restrict__ ss) {
    __shared__ int sdeg[SPAN];
    __shared__ int sc[SPAN];
    int b = blockIdx.x;
    int lo = b << SH;
    int bstart = bbase[b];
    int bn = bcnt[b];
    int t = threadIdx.x;

    sdeg[t] = 0;
    __syncthreads();
    for (int i = t; i < bn; i += 512)
        atomicAdd(&sdeg[ebuf[bstart + i].y - lo], 1);
    __syncthreads();

    int a = sdeg[t];
    sc[t] = a;
    __syncthreads();
    for (int off = 1; off < SPAN; off <<= 1) {
        int v = sc[t];
        int add = (t >= off) ? sc[t - off] : 0;
        __syncthreads();
        sc[t] = v + add;
        __syncthreads();
    }
    int ex = sc[t] - a;                        // exclusive prefix
    sdeg[t] = ex;                              // local cursor
    if (lo + t < N_NODES) rp[lo + t] = bstart + ex;
    __syncthreads();

    for (int i = t; i < bn; i += 512) {
        int2 p = ebuf[bstart + i];
        int pos = atomicAdd(&sdeg[p.y - lo], 1);   // LDS atomic
        ss[bstart + pos] = p.x;
    }
}

// ---------------------------------------------------------------------------
// f32 -> bf16 conversion of input features
// ---------------------------------------------------------------------------
__global__ void __launch_bounds__(256)
conv_kernel(const float* __restrict__ x, ushort* __restrict__ xh) {
    int i = blockIdx.x * 256 + threadIdx.x;
    float4 v = ((const float4*)x)[i];
    ushort4 o;
    o.x = f2bf(v.x); o.y = f2bf(v.y); o.z = f2bf(v.z); o.w = f2bf(v.w);
    ((ushort4*)xh)[i] = o;
}

// ---------------------------------------------------------------------------
// Fused layer (unchanged from round 9): CSR gather-mean (bf16 pair-load) ->
// LDS cin (bf16) -> MFMA GEMV + bias + ReLU. 512 thr = 8 waves, 32 nodes/blk.
// ---------------------------------------------------------------------------
__global__ void __launch_bounds__(512)
fused_sage_kernel(const ushort* __restrict__ xh,
                  const int* __restrict__ rp,
                  const int* __restrict__ ss,
                  const ushort* __restrict__ Wt,   // [64][LDW] bf16
                  const float* __restrict__ bias,
                  ushort* __restrict__ out_bf,
                  float* __restrict__ out_f)
{
    __shared__ ushort sWt[F * LDW];
    __shared__ ushort cin[32 * LDW];

    {
        const int* src = (const int*)Wt;
        int* dst = (int*)sWt;
        for (int i = threadIdx.x; i < F * LDW / 2; i += 512) dst[i] = src[i];
    }

    const int w    = threadIdx.x >> 6;
    const int lane = threadIdx.x & 63;
    const int half = lane >> 5;
    const int p    = lane & 31;

    const unsigned int* __restrict__ xw = (const unsigned int*)xh;

    for (int q = 0; q < 4; ++q) {
        const int n = blockIdx.x * 32 + w * 4 + q;
        int start = rp[n];
        int end   = rp[n + 1];
        float ax = 0.0f, ay = 0.0f;

        int i = start;
        for (; i + 8 <= end; i += 8) {
            int e0 = i + half;
            int s0 = ss[e0], s1 = ss[e0 + 2], s2 = ss[e0 + 4], s3 = ss[e0 + 6];
            unsigned int u0 = xw[(size_t)s0 * 32 + p];
            unsigned int u1 = xw[(size_t)s1 * 32 + p];
            unsigned int u2 = xw[(size_t)s2 * 32 + p];
            unsigned int u3 = xw[(size_t)s3 * 32 + p];
            ax += bf2f((ushort)u0) + bf2f((ushort)u1)
                + bf2f((ushort)u2) + bf2f((ushort)u3);
            ay += bf2f((ushort)(u0 >> 16)) + bf2f((ushort)(u1 >> 16))
                + bf2f((ushort)(u2 >> 16)) + bf2f((ushort)(u3 >> 16));
        }
        for (; i + 2 <= end; i += 2) {
            int s0 = ss[i + half];
            unsigned int u0 = xw[(size_t)s0 * 32 + p];
            ax += bf2f((ushort)u0);
            ay += bf2f((ushort)(u0 >> 16));
        }
        if (i < end && half == 0) {
            int s0 = ss[i];
            unsigned int u0 = xw[(size_t)s0 * 32 + p];
            ax += bf2f((ushort)u0);
            ay += bf2f((ushort)(u0 >> 16));
        }
        ax += __shfl_xor(ax, 32);
        ay += __shfl_xor(ay, 32);

        if (half == 0) {
            unsigned int* crow = (unsigned int*)&cin[(w * 4 + q) * LDW];
            crow[p] = xw[(size_t)n * 32 + p];
            float scale = 1.0f / fmaxf((float)(end - start), 1.0f);
            unsigned int lo = f2bf(ax * scale);
            unsigned int hi = f2bf(ay * scale);
            crow[32 + p] = (hi << 16) | lo;
        }
    }
    __syncthreads();

    const int Mt = w >> 2, Nt = w & 3;
    const int r16 = lane & 15, g4 = lane >> 4;
    floatx4 acc = {0.0f, 0.0f, 0.0f, 0.0f};
    #pragma unroll
    for (int ks = 0; ks < 4; ++ks) {
        short8 a = *(const short8*)&cin[(Mt * 16 + r16) * LDW + ks * 32 + g4 * 8];
        short8 b = *(const short8*)&sWt[(Nt * 16 + r16) * LDW + ks * 32 + g4 * 8];
        acc = __builtin_amdgcn_mfma_f32_16x16x32_bf16(a, b, acc, 0, 0, 0);
    }
    const int feat = Nt * 16 + r16;
    const float bv = bias[feat];
    #pragma unroll
    for (int reg = 0; reg < 4; ++reg) {
        int node = blockIdx.x * 32 + Mt * 16 + g4 * 4 + reg;
        float r = fmaxf(acc[reg] + bv, 0.0f);
        if (out_bf) out_bf[(size_t)node * F + feat] = f2bf(r);
        if (out_f)  out_f [(size_t)node * F + feat] = r;
    }
}

extern "C" void kernel_launch(void* const* d_in, const int* in_sizes, int n_in,
                              void* d_out, int out_size, void* d_ws, size_t ws_size,
                              hipStream_t stream) {
    const float* x    = (const float*)d_in[0];
    const int*   esrc = (const int*)d_in[1];
    const int*   edst = (const int*)d_in[2];
    const float* W1   = (const float*)d_in[3];
    const float* b1   = (const float*)d_in[4];
    const float* W2   = (const float*)d_in[5];
    const float* b2   = (const float*)d_in[6];
    float* out = (float*)d_out;

    // Workspace layout (16B-aligned blocks):
    int*    bcnt   = (int*)d_ws;                       // 256
    int*    bbase  = bcnt + NBK;                       // 256
    int*    bcur   = bbase + NBK;                      // 256
    int*    rp     = bcur + NBK;                       // 100001 (+pad)
    int*    ss     = rp + (N_NODES + 8);               // 1600000
    ushort* xh     = (ushort*)(ss + N_EDGES);          // 6.4M bf16 (12.8 MB)
    ushort* h1h    = xh + (size_t)N_NODES * F;         // 6.4M bf16 (12.8 MB)
    int2*   ebuf   = (int2*)h1h;                       // aliases h1h (pre-sage1)
    ushort* Wt1g   = h1h + (size_t)N_NODES * F;        // 64*LDW bf16
    ushort* Wt2g   = Wt1g + F * LDW;                   // 64*LDW bf16

    const int NB = N_NODES / 32;                 // 3125 (exact)
    const int CB = (N_NODES * F / 4) / 256;      // 6250 (exact)

    hipMemsetAsync(bcnt, 0, NBK * 4, stream);
    count_kernel<<<COUNT_BLOCKS, 256, 0, stream>>>(edst, bcnt);
    scan_prep_kernel<<<1, 512, 0, stream>>>(bcnt, bbase, bcur, rp,
                                            W1, W2, Wt1g, Wt2g);
    part_kernel<<<PART_BLOCKS, PART_T, 0, stream>>>(esrc, edst, bcur, ebuf);
    csr_bucket_kernel<<<NBK_USED, 512, 0, stream>>>(ebuf, bbase, bcnt, rp, ss);
    conv_kernel<<<CB, 256, 0, stream>>>(x, xh);

    fused_sage_kernel<<<NB, 512, 0, stream>>>(xh,  rp, ss, Wt1g, b1, h1h, nullptr);
    fused_sage_kernel<<<NB, 512, 0, stream>>>(h1h, rp, ss, Wt2g, b2, nullptr, out);
}

// Round 12
// 294.731 us; speedup vs baseline: 3.5741x; 1.0296x over previous
//
#include <hip/hip_runtime.h>
#include <hip/hip_bf16.h>

// GraphSAGE forward, 2 layers. N=100000, E=1600000, F=64, W: [128,64].
//
// Round 12: round-11: fused_sage 2x73.5 us (unchanged), build ~156 us.
// Levers: (1) fused_sage gather restructured -- each HALF-WAVE owns one
// node (lane p <-> feature dword p), 8-edge-deep load batches (8 rows in
// flight/lane), no cross-half shuffles; (2) count fused into conv (one
// launch, disjoint block ranges). CSR build otherwise unchanged.

constexpr int N_NODES = 100000;
constexpr int N_EDGES = 1600000;
constexpr int F = 64;
constexpr int SH = 9;                          // bucket shift (span 512)
constexpr int SPAN = 1 << SH;                  // 512
constexpr int NBK = 256;                       // bucket array size
constexpr int NBK_USED = (N_NODES + SPAN - 1) / SPAN;  // 196
constexpr int PART_T = 512;
constexpr int PART_E = 4096;
constexpr int PART_BLOCKS = (N_EDGES + PART_E - 1) / PART_E;   // 391
constexpr int COUNT_BLOCKS = (N_EDGES + 2047) / 2048;          // 782
constexpr int CONV_BLOCKS = (N_NODES * F / 4) / 256;           // 6250
constexpr int LDW = 136;                       // padded bf16 row

typedef short short8 __attribute__((ext_vector_type(8)));
typedef float floatx4 __attribute__((ext_vector_type(4)));

// ---- bf16 helpers (RN-even; inputs are finite) ----
__device__ __forceinline__ float bf2f(ushort u) {
    union { unsigned int i; float f; } c; c.i = (unsigned int)u << 16; return c.f;
}
__device__ __forceinline__ ushort f2bf(float v) {
    union { float f; unsigned int i; } c; c.f = v;
    unsigned int r = c.i + 0x7fffu + ((c.i >> 16) & 1u);
    return (ushort)(r >> 16);
}

// ---------------------------------------------------------------------------
// count (bucket histogram) + conv (f32->bf16) fused: disjoint block ranges.
// ---------------------------------------------------------------------------
__global__ void __launch_bounds__(256)
count_conv_kernel(const int* __restrict__ edst, int* __restrict__ bcnt,
                  const float* __restrict__ x, ushort* __restrict__ xh) {
    int t = threadIdx.x;
    if (blockIdx.x < COUNT_BLOCKS) {
        __shared__ int lb[NBK];
        lb[t] = 0;
        __syncthreads();
        int base = blockIdx.x * 2048;
        #pragma unroll
        for (int k = 0; k < 8; ++k) {
            int e = base + k * 256 + t;
            if (e < N_EDGES) atomicAdd(&lb[edst[e] >> SH], 1);
        }
        __syncthreads();
        if (lb[t]) atomicAdd(&bcnt[t], lb[t]);
    } else {
        int i = (blockIdx.x - COUNT_BLOCKS) * 256 + t;
        float4 v = ((const float4*)x)[i];
        ushort4 o;
        o.x = f2bf(v.x); o.y = f2bf(v.y); o.z = f2bf(v.z); o.w = f2bf(v.w);
        ((ushort4*)xh)[i] = o;
    }
}

// Bucket scan (serial over LDS) + W1/W2 transpose-convert. One block.
__global__ void __launch_bounds__(512)
scan_prep_kernel(const int* __restrict__ bcnt, int* __restrict__ bbase,
                 int* __restrict__ bcur, int* __restrict__ rp,
                 const float* __restrict__ W1, const float* __restrict__ W2,
                 ushort* __restrict__ Wt1, ushort* __restrict__ Wt2) {
    __shared__ int sb[NBK];
    int t = threadIdx.x;
    if (t < NBK) sb[t] = bcnt[t];
    __syncthreads();
    if (t == 0) {
        int run = 0;
        for (int i = 0; i < NBK; ++i) { int v = sb[i]; sb[i] = run; run += v; }
        rp[N_NODES] = run;   // = E
    }
    __syncthreads();
    if (t < NBK) { bbase[t] = sb[t]; bcur[t] = sb[t]; }
    for (int i = t; i < 2 * F * F; i += 512) {
        int k = i >> 6, f = i & 63;
        Wt1[f * LDW + k] = f2bf(W1[i]);
        Wt2[f * LDW + k] = f2bf(W2[i]);
    }
}

// Block-level counting sort of 4096 edges into 256 dst-buckets; wave-parallel
// coalesced append into the partitioned edge buffer.
__global__ void __launch_bounds__(PART_T)
part_kernel(const int* __restrict__ esrc, const int* __restrict__ edst,
            int* __restrict__ bcur, int2* __restrict__ ebuf) {
    __shared__ int cnt[NBK];
    __shared__ int lbase[NBK];
    __shared__ int gbase[NBK];
    __shared__ int2 stage[PART_E];        // 32 KB
    int t = threadIdx.x;
    if (t < NBK) cnt[t] = 0;
    __syncthreads();
    int base = blockIdx.x * PART_E;
    int2 ed[8]; int bk[8]; int rk[8];
    #pragma unroll
    for (int k = 0; k < 8; ++k) {
        int e = base + k * PART_T + t;
        if (e < N_EDGES) {
            ed[k].x = esrc[e];
            ed[k].y = edst[e];
            bk[k] = ed[k].y >> SH;
            rk[k] = atomicAdd(&cnt[bk[k]], 1);
        } else {
            bk[k] = -1; rk[k] = 0; ed[k] = make_int2(0, 0);
        }
    }
    __syncthreads();
    // parallel exclusive scan of cnt[256]
    {
        int v = 0;
        if (t < NBK) { v = cnt[t]; lbase[t] = v; }
        __syncthreads();
        for (int off = 1; off < NBK; off <<= 1) {
            int add = 0;
            if (t < NBK && t >= off) add = lbase[t - off];
            __syncthreads();
            if (t < NBK) lbase[t] += add;
            __syncthreads();
        }
        if (t < NBK) lbase[t] -= v;
    }
    __syncthreads();
    if (t < NBK) gbase[t] = cnt[t] ? atomicAdd(&bcur[t], cnt[t]) : 0;
    __syncthreads();
    #pragma unroll
    for (int k = 0; k < 8; ++k)
        if (bk[k] >= 0) stage[lbase[bk[k]] + rk[k]] = ed[k];
    __syncthreads();
    // wave-parallel output: wave w copies buckets w*32 .. w*32+31
    {
        int w = t >> 6, lane = t & 63;
        for (int b = w * 32; b < w * 32 + 32; ++b) {
            int len = cnt[b], l0 = lbase[b], g0 = gbase[b];
            for (int i = lane; i < len; i += 64) ebuf[g0 + i] = stage[l0 + i];
        }
    }
}

// One block per bucket (196 blocks, 512 thr): LDS deg hist over 512 nodes,
// exclusive scan -> rp slice, LDS-cursor fill -> ss slice. No global atomics.
__global__ void __launch_bounds__(512)
csr_bucket_kernel(const int2* __restrict__ ebuf, const int* __restrict__ bbase,
                  const int* __restrict__ bcnt,
                  int* __restrict__ rp, int* __restrict__ ss) {
    __shared__ int sdeg[SPAN];
    __shared__ int sc[SPAN];
    int b = blockIdx.x;
    int lo = b << SH;
    int bstart = bbase[b];
    int bn = bcnt[b];
    int t = threadIdx.x;

    sdeg[t] = 0;
    __syncthreads();
    for (int i = t; i < bn; i += 512)
        atomicAdd(&sdeg[ebuf[bstart + i].y - lo], 1);
    __syncthreads();

    int a = sdeg[t];
    sc[t] = a;
    __syncthreads();
    for (int off = 1; off < SPAN; off <<= 1) {
        int v = sc[t];
        int add = (t >= off) ? sc[t - off] : 0;
        __syncthreads();
        sc[t] = v + add;
        __syncthreads();
    }
    int ex = sc[t] - a;
    sdeg[t] = ex;
    if (lo + t < N_NODES) rp[lo + t] = bstart + ex;
    __syncthreads();

    for (int i = t; i < bn; i += 512) {
        int2 p = ebuf[bstart + i];
        int pos = atomicAdd(&sdeg[p.y - lo], 1);   // LDS atomic
        ss[bstart + pos] = p.x;
    }
}

// ---------------------------------------------------------------------------
// Fused layer: CSR gather-mean + concat + MFMA GEMV + bias + ReLU.
// 512 thr = 8 waves = 16 half-waves; 32 nodes/block, 2 nodes per half-wave.
// Gather: half-wave owns a node; lane p owns feature dword p (feats 2p,2p+1);
// 8-edge-deep batches -> 8 independent row loads in flight per lane.
// ---------------------------------------------------------------------------
__global__ void __launch_bounds__(512)
fused_sage_kernel(const ushort* __restrict__ xh,
                  const int* __restrict__ rp,
                  const int* __restrict__ ss,
                  const ushort* __restrict__ Wt,   // [64][LDW] bf16
                  const float* __restrict__ bias,
                  ushort* __restrict__ out_bf,
                  float* __restrict__ out_f)
{
    __shared__ ushort sWt[F * LDW];
    __shared__ ushort cin[32 * LDW];

    {
        const int* src = (const int*)Wt;
        int* dst = (int*)sWt;
        for (int i = threadIdx.x; i < F * LDW / 2; i += 512) dst[i] = src[i];
    }

    const int w    = threadIdx.x >> 6;
    const int lane = threadIdx.x & 63;
    const int half = lane >> 5;
    const int p    = lane & 31;

    const unsigned int* __restrict__ xw = (const unsigned int*)xh;

    #pragma unroll
    for (int q = 0; q < 2; ++q) {
        const int n_row = w * 4 + half * 2 + q;          // 0..31
        const int n = blockIdx.x * 32 + n_row;
        int start = rp[n];
        int end   = rp[n + 1];
        float ax = 0.0f, ay = 0.0f;

        int i = start;
        for (; i + 8 <= end; i += 8) {
            int s0 = ss[i],     s1 = ss[i + 1], s2 = ss[i + 2], s3 = ss[i + 3];
            int s4 = ss[i + 4], s5 = ss[i + 5], s6 = ss[i + 6], s7 = ss[i + 7];
            unsigned int u0 = xw[(size_t)s0 * 32 + p];
            unsigned int u1 = xw[(size_t)s1 * 32 + p];
            unsigned int u2 = xw[(size_t)s2 * 32 + p];
            unsigned int u3 = xw[(size_t)s3 * 32 + p];
            unsigned int u4 = xw[(size_t)s4 * 32 + p];
            unsigned int u5 = xw[(size_t)s5 * 32 + p];
            unsigned int u6 = xw[(size_t)s6 * 32 + p];
            unsigned int u7 = xw[(size_t)s7 * 32 + p];
            ax += bf2f((ushort)u0) + bf2f((ushort)u1)
                + bf2f((ushort)u2) + bf2f((ushort)u3)
                + bf2f((ushort)u4) + bf2f((ushort)u5)
                + bf2f((ushort)u6) + bf2f((ushort)u7);
            ay += bf2f((ushort)(u0 >> 16)) + bf2f((ushort)(u1 >> 16))
                + bf2f((ushort)(u2 >> 16)) + bf2f((ushort)(u3 >> 16))
                + bf2f((ushort)(u4 >> 16)) + bf2f((ushort)(u5 >> 16))
                + bf2f((ushort)(u6 >> 16)) + bf2f((ushort)(u7 >> 16));
        }
        for (; i < end; ++i) {
            unsigned int u0 = xw[(size_t)ss[i] * 32 + p];
            ax += bf2f((ushort)u0);
            ay += bf2f((ushort)(u0 >> 16));
        }

        unsigned int* crow = (unsigned int*)&cin[n_row * LDW];
        crow[p] = xw[(size_t)n * 32 + p];                // self feats 2p,2p+1
        float scale = 1.0f / fmaxf((float)(end - start), 1.0f);
        unsigned int lo = f2bf(ax * scale);
        unsigned int hi = f2bf(ay * scale);
        crow[32 + p] = (hi << 16) | lo;                  // mean feats
    }
    __syncthreads();

    const int Mt = w >> 2, Nt = w & 3;
    const int r16 = lane & 15, g4 = lane >> 4;
    floatx4 acc = {0.0f, 0.0f, 0.0f, 0.0f};
    #pragma unroll
    for (int ks = 0; ks < 4; ++ks) {
        short8 a = *(const short8*)&cin[(Mt * 16 + r16) * LDW + ks * 32 + g4 * 8];
        short8 b = *(const short8*)&sWt[(Nt * 16 + r16) * LDW + ks * 32 + g4 * 8];
        acc = __builtin_amdgcn_mfma_f32_16x16x32_bf16(a, b, acc, 0, 0, 0);
    }
    const int feat = Nt * 16 + r16;
    const float bv = bias[feat];
    #pragma unroll
    for (int reg = 0; reg < 4; ++reg) {
        int node = blockIdx.x * 32 + Mt * 16 + g4 * 4 + reg;
        float r = fmaxf(acc[reg] + bv, 0.0f);
        if (out_bf) out_bf[(size_t)node * F + feat] = f2bf(r);
        if (out_f)  out_f [(size_t)node * F + feat] = r;
    }
}

extern "C" void kernel_launch(void* const* d_in, const int* in_sizes, int n_in,
                              void* d_out, int out_size, void* d_ws, size_t ws_size,
                              hipStream_t stream) {
    const float* x    = (const float*)d_in[0];
    const int*   esrc = (const int*)d_in[1];
    const int*   edst = (const int*)d_in[2];
    const float* W1   = (const float*)d_in[3];
    const float* b1   = (const float*)d_in[4];
    const float* W2   = (const float*)d_in[5];
    const float* b2   = (const float*)d_in[6];
    float* out = (float*)d_out;

    // Workspace layout (16B-aligned blocks):
    int*    bcnt   = (int*)d_ws;                       // 256
    int*    bbase  = bcnt + NBK;                       // 256
    int*    bcur   = bbase + NBK;                      // 256
    int*    rp     = bcur + NBK;                       // 100001 (+pad)
    int*    ss     = rp + (N_NODES + 8);               // 1600000
    ushort* xh     = (ushort*)(ss + N_EDGES);          // 6.4M bf16 (12.8 MB)
    ushort* h1h    = xh + (size_t)N_NODES * F;         // 6.4M bf16 (12.8 MB)
    int2*   ebuf   = (int2*)h1h;                       // aliases h1h (pre-sage1)
    ushort* Wt1g   = h1h + (size_t)N_NODES * F;        // 64*LDW bf16
    ushort* Wt2g   = Wt1g + F * LDW;                   // 64*LDW bf16

    const int NB = N_NODES / 32;                 // 3125 (exact)

    hipMemsetAsync(bcnt, 0, NBK * 4, stream);
    count_conv_kernel<<<COUNT_BLOCKS + CONV_BLOCKS, 256, 0, stream>>>(
        edst, bcnt, x, xh);
    scan_prep_kernel<<<1, 512, 0, stream>>>(bcnt, bbase, bcur, rp,
                                            W1, W2, Wt1g, Wt2g);
    part_kernel<<<PART_BLOCKS, PART_T, 0, stream>>>(esrc, edst, bcur, ebuf);
    csr_bucket_kernel<<<NBK_USED, 512, 0, stream>>>(ebuf, bbase, bcnt, rp, ss);

    fused_sage_kernel<<<NB, 512, 0, stream>>>(xh,  rp, ss, Wt1g, b1, h1h, nullptr);
    fused_sage_kernel<<<NB, 512, 0, stream>>>(h1h, rp, ss, Wt2g, b2, nullptr, out);
}

// Round 13
// 287.561 us; speedup vs baseline: 3.6632x; 1.0249x over previous
//
#include <hip/hip_runtime.h>
#include <hip/hip_bf16.h>

// GraphSAGE forward, 2 layers. N=100000, E=1600000, F=64, W: [128,64].
//
// Round 13: round-12: fused_sage 2x72 us (ILP restructure null -> gather is
// at random-128B-granule memory-system throughput, not latency-bound).
// Build ~150 us, structure-bound. Levers (build only):
//  (1) count: grid-stride 256 blocks (flush atomics 200K -> 65K),
//  (2) part: PART_E=8192 two-pass (count pass + placement pass with LDS
//      cursors seeded to lbase; no register staging arrays; 196 blocks,
//      half the bcur atomics, 2x longer coalesced output runs),
//  (3) scan_prep: parallel 256-lane scan.
// fused_sage / csr_bucket unchanged.

constexpr int N_NODES = 100000;
constexpr int N_EDGES = 1600000;
constexpr int F = 64;
constexpr int SH = 9;                          // bucket shift (span 512)
constexpr int SPAN = 1 << SH;                  // 512
constexpr int NBK = 256;                       // bucket array size
constexpr int NBK_USED = (N_NODES + SPAN - 1) / SPAN;  // 196
constexpr int PART_T = 512;
constexpr int PART_E = 8192;
constexpr int PART_BLOCKS = (N_EDGES + PART_E - 1) / PART_E;   // 196
constexpr int COUNT_GRID = 256;                // grid-stride count blocks
constexpr int CONV_BLOCKS = (N_NODES * F / 4) / 256;           // 6250
constexpr int LDW = 136;                       // padded bf16 row

typedef short short8 __attribute__((ext_vector_type(8)));
typedef float floatx4 __attribute__((ext_vector_type(4)));

// ---- bf16 helpers (RN-even; inputs are finite) ----
__device__ __forceinline__ float bf2f(ushort u) {
    union { unsigned int i; float f; } c; c.i = (unsigned int)u << 16; return c.f;
}
__device__ __forceinline__ ushort f2bf(float v) {
    union { float f; unsigned int i; } c; c.f = v;
    unsigned int r = c.i + 0x7fffu + ((c.i >> 16) & 1u);
    return (ushort)(r >> 16);
}

// ---------------------------------------------------------------------------
// count (grid-stride bucket histogram) + conv (f32->bf16), disjoint blocks.
// ---------------------------------------------------------------------------
__global__ void __launch_bounds__(256)
count_conv_kernel(const int* __restrict__ edst, int* __restrict__ bcnt,
                  const float* __restrict__ x, ushort* __restrict__ xh) {
    int t = threadIdx.x;
    if (blockIdx.x < COUNT_GRID) {
        __shared__ int lb[NBK];
        lb[t] = 0;
        __syncthreads();
        for (int e = blockIdx.x * 256 + t; e < N_EDGES; e += COUNT_GRID * 256)
            atomicAdd(&lb[edst[e] >> SH], 1);
        __syncthreads();
        if (lb[t]) atomicAdd(&bcnt[t], lb[t]);
    } else {
        int i = (blockIdx.x - COUNT_GRID) * 256 + t;
        float4 v = ((const float4*)x)[i];
        ushort4 o;
        o.x = f2bf(v.x); o.y = f2bf(v.y); o.z = f2bf(v.z); o.w = f2bf(v.w);
        ((ushort4*)xh)[i] = o;
    }
}

// Parallel bucket scan + W1/W2 transpose-convert. One block.
__global__ void __launch_bounds__(512)
scan_prep_kernel(const int* __restrict__ bcnt, int* __restrict__ bbase,
                 int* __restrict__ bcur, int* __restrict__ rp,
                 const float* __restrict__ W1, const float* __restrict__ W2,
                 ushort* __restrict__ Wt1, ushort* __restrict__ Wt2) {
    __shared__ int sv[NBK];
    __shared__ int sx[NBK];
    int t = threadIdx.x;
    if (t < NBK) { sv[t] = bcnt[t]; sx[t] = sv[t]; }
    __syncthreads();
    for (int off = 1; off < NBK; off <<= 1) {
        int add = 0;
        if (t < NBK && t >= off) add = sx[t - off];
        __syncthreads();
        if (t < NBK) sx[t] += add;
        __syncthreads();
    }
    if (t < NBK) {
        int ex = sx[t] - sv[t];
        bbase[t] = ex;
        bcur[t]  = ex;
        if (t == NBK - 1) rp[N_NODES] = sx[t];   // = E
    }
    for (int i = t; i < 2 * F * F; i += 512) {
        int k = i >> 6, f = i & 63;
        Wt1[f * LDW + k] = f2bf(W1[i]);
        Wt2[f * LDW + k] = f2bf(W2[i]);
    }
}

// Two-pass counting sort of 8192 edges into 256 dst-buckets.
// Pass 1 counts; scan; LDS cursors seeded to lbase; pass 2 re-reads edges
// and places into the 64KB LDS stage; wave-parallel coalesced output.
__global__ void __launch_bounds__(PART_T)
part_kernel(const int* __restrict__ esrc, const int* __restrict__ edst,
            int* __restrict__ bcur, int2* __restrict__ ebuf) {
    __shared__ int cnt[NBK];      // counts, then LDS cursors
    __shared__ int lbase[NBK];
    __shared__ int gbase[NBK];
    __shared__ int2 stage[PART_E];        // 64 KB
    int t = threadIdx.x;
    if (t < NBK) cnt[t] = 0;
    __syncthreads();
    int base = blockIdx.x * PART_E;
    #pragma unroll
    for (int k = 0; k < PART_E / PART_T; ++k) {
        int e = base + k * PART_T + t;
        if (e < N_EDGES) atomicAdd(&cnt[edst[e] >> SH], 1);
    }
    __syncthreads();
    // parallel exclusive scan of cnt[256] -> lbase
    {
        int v = 0;
        if (t < NBK) { v = cnt[t]; lbase[t] = v; }
        __syncthreads();
        for (int off = 1; off < NBK; off <<= 1) {
            int add = 0;
            if (t < NBK && t >= off) add = lbase[t - off];
            __syncthreads();
            if (t < NBK) lbase[t] += add;
            __syncthreads();
        }
        if (t < NBK) lbase[t] -= v;
    }
    __syncthreads();
    if (t < NBK) {
        gbase[t] = cnt[t] ? atomicAdd(&bcur[t], cnt[t]) : 0;
        cnt[t] = lbase[t];                 // seed LDS cursor
    }
    __syncthreads();
    #pragma unroll
    for (int k = 0; k < PART_E / PART_T; ++k) {
        int e = base + k * PART_T + t;
        if (e < N_EDGES) {
            int s = esrc[e], d = edst[e];
            int pos = atomicAdd(&cnt[d >> SH], 1);
            stage[pos] = make_int2(s, d);
        }
    }
    __syncthreads();
    // wave-parallel output: wave w copies buckets w*32 .. w*32+31
    {
        int w = t >> 6, lane = t & 63;
        for (int b = w * 32; b < w * 32 + 32; ++b) {
            int g0 = gbase[b], l0 = lbase[b];
            int len = cnt[b] - l0;         // cursor advanced by count
            for (int i = lane; i < len; i += 64) ebuf[g0 + i] = stage[l0 + i];
        }
    }
}

// One block per bucket (196 blocks, 512 thr): LDS deg hist over 512 nodes,
// exclusive scan -> rp slice, LDS-cursor fill -> ss slice. No global atomics.
__global__ void __launch_bounds__(512)
csr_bucket_kernel(const int2* __restrict__ ebuf, const int* __restrict__ bbase,
                  const int* __restrict__ bcnt,
                  int* __restrict__ rp, int* __restrict__ ss) {
    __shared__ int sdeg[SPAN];
    __shared__ int sc[SPAN];
    int b = blockIdx.x;
    int lo = b << SH;
    int bstart = bbase[b];
    int bn = bcnt[b];
    int t = threadIdx.x;

    sdeg[t] = 0;
    __syncthreads();
    for (int i = t; i < bn; i += 512)
        atomicAdd(&sdeg[ebuf[bstart + i].y - lo], 1);
    __syncthreads();

    int a = sdeg[t];
    sc[t] = a;
    __syncthreads();
    for (int off = 1; off < SPAN; off <<= 1) {
        int v = sc[t];
        int add = (t >= off) ? sc[t - off] : 0;
        __syncthreads();
        sc[t] = v + add;
        __syncthreads();
    }
    int ex = sc[t] - a;
    sdeg[t] = ex;
    if (lo + t < N_NODES) rp[lo + t] = bstart + ex;
    __syncthreads();

    for (int i = t; i < bn; i += 512) {
        int2 p = ebuf[bstart + i];
        int pos = atomicAdd(&sdeg[p.y - lo], 1);   // LDS atomic
        ss[bstart + pos] = p.x;
    }
}

// ---------------------------------------------------------------------------
// Fused layer (unchanged from round 12): CSR gather-mean + concat + MFMA GEMV.
// 512 thr = 8 waves = 16 half-waves; 32 nodes/block, 2 nodes per half-wave.
// ---------------------------------------------------------------------------
__global__ void __launch_bounds__(512)
fused_sage_kernel(const ushort* __restrict__ xh,
                  const int* __restrict__ rp,
                  const int* __restrict__ ss,
                  const ushort* __restrict__ Wt,   // [64][LDW] bf16
                  const float* __restrict__ bias,
                  ushort* __restrict__ out_bf,
                  float* __restrict__ out_f)
{
    __shared__ ushort sWt[F * LDW];
    __shared__ ushort cin[32 * LDW];

    {
        const int* src = (const int*)Wt;
        int* dst = (int*)sWt;
        for (int i = threadIdx.x; i < F * LDW / 2; i += 512) dst[i] = src[i];
    }

    const int w    = threadIdx.x >> 6;
    const int lane = threadIdx.x & 63;
    const int half = lane >> 5;
    const int p    = lane & 31;

    const unsigned int* __restrict__ xw = (const unsigned int*)xh;

    #pragma unroll
    for (int q = 0; q < 2; ++q) {
        const int n_row = w * 4 + half * 2 + q;          // 0..31
        const int n = blockIdx.x * 32 + n_row;
        int start = rp[n];
        int end   = rp[n + 1];
        float ax = 0.0f, ay = 0.0f;

        int i = start;
        for (; i + 8 <= end; i += 8) {
            int s0 = ss[i],     s1 = ss[i + 1], s2 = ss[i + 2], s3 = ss[i + 3];
            int s4 = ss[i + 4], s5 = ss[i + 5], s6 = ss[i + 6], s7 = ss[i + 7];
            unsigned int u0 = xw[(size_t)s0 * 32 + p];
            unsigned int u1 = xw[(size_t)s1 * 32 + p];
            unsigned int u2 = xw[(size_t)s2 * 32 + p];
            unsigned int u3 = xw[(size_t)s3 * 32 + p];
            unsigned int u4 = xw[(size_t)s4 * 32 + p];
            unsigned int u5 = xw[(size_t)s5 * 32 + p];
            unsigned int u6 = xw[(size_t)s6 * 32 + p];
            unsigned int u7 = xw[(size_t)s7 * 32 + p];
            ax += bf2f((ushort)u0) + bf2f((ushort)u1)
                + bf2f((ushort)u2) + bf2f((ushort)u3)
                + bf2f((ushort)u4) + bf2f((ushort)u5)
                + bf2f((ushort)u6) + bf2f((ushort)u7);
            ay += bf2f((ushort)(u0 >> 16)) + bf2f((ushort)(u1 >> 16))
                + bf2f((ushort)(u2 >> 16)) + bf2f((ushort)(u3 >> 16))
                + bf2f((ushort)(u4 >> 16)) + bf2f((ushort)(u5 >> 16))
                + bf2f((ushort)(u6 >> 16)) + bf2f((ushort)(u7 >> 16));
        }
        for (; i < end; ++i) {
            unsigned int u0 = xw[(size_t)ss[i] * 32 + p];
            ax += bf2f((ushort)u0);
            ay += bf2f((ushort)(u0 >> 16));
        }

        unsigned int* crow = (unsigned int*)&cin[n_row * LDW];
        crow[p] = xw[(size_t)n * 32 + p];                // self feats 2p,2p+1
        float scale = 1.0f / fmaxf((float)(end - start), 1.0f);
        unsigned int lo = f2bf(ax * scale);
        unsigned int hi = f2bf(ay * scale);
        crow[32 + p] = (hi << 16) | lo;                  // mean feats
    }
    __syncthreads();

    const int Mt = w >> 2, Nt = w & 3;
    const int r16 = lane & 15, g4 = lane >> 4;
    floatx4 acc = {0.0f, 0.0f, 0.0f, 0.0f};
    #pragma unroll
    for (int ks = 0; ks < 4; ++ks) {
        short8 a = *(const short8*)&cin[(Mt * 16 + r16) * LDW + ks * 32 + g4 * 8];
        short8 b = *(const short8*)&sWt[(Nt * 16 + r16) * LDW + ks * 32 + g4 * 8];
        acc = __builtin_amdgcn_mfma_f32_16x16x32_bf16(a, b, acc, 0, 0, 0);
    }
    const int feat = Nt * 16 + r16;
    const float bv = bias[feat];
    #pragma unroll
    for (int reg = 0; reg < 4; ++reg) {
        int node = blockIdx.x * 32 + Mt * 16 + g4 * 4 + reg;
        float r = fmaxf(acc[reg] + bv, 0.0f);
        if (out_bf) out_bf[(size_t)node * F + feat] = f2bf(r);
        if (out_f)  out_f [(size_t)node * F + feat] = r;
    }
}

extern "C" void kernel_launch(void* const* d_in, const int* in_sizes, int n_in,
                              void* d_out, int out_size, void* d_ws, size_t ws_size,
                              hipStream_t stream) {
    const float* x    = (const float*)d_in[0];
    const int*   esrc = (const int*)d_in[1];
    const int*   edst = (const int*)d_in[2];
    const float* W1   = (const float*)d_in[3];
    const float* b1   = (const float*)d_in[4];
    const float* W2   = (const float*)d_in[5];
    const float* b2   = (const float*)d_in[6];
    float* out = (float*)d_out;

    // Workspace layout (16B-aligned blocks):
    int*    bcnt   = (int*)d_ws;                       // 256
    int*    bbase  = bcnt + NBK;                       // 256
    int*    bcur   = bbase + NBK;                      // 256
    int*    rp     = bcur + NBK;                       // 100001 (+pad)
    int*    ss     = rp + (N_NODES + 8);               // 1600000
    ushort* xh     = (ushort*)(ss + N_EDGES);          // 6.4M bf16 (12.8 MB)
    ushort* h1h    = xh + (size_t)N_NODES * F;         // 6.4M bf16 (12.8 MB)
    int2*   ebuf   = (int2*)h1h;                       // aliases h1h (pre-sage1)
    ushort* Wt1g   = h1h + (size_t)N_NODES * F;        // 64*LDW bf16
    ushort* Wt2g   = Wt1g + F * LDW;                   // 64*LDW bf16

    const int NB = N_NODES / 32;                 // 3125 (exact)

    hipMemsetAsync(bcnt, 0, NBK * 4, stream);
    count_conv_kernel<<<COUNT_GRID + CONV_BLOCKS, 256, 0, stream>>>(
        edst, bcnt, x, xh);
    scan_prep_kernel<<<1, 512, 0, stream>>>(bcnt, bbase, bcur, rp,
                                            W1, W2, Wt1g, Wt2g);
    part_kernel<<<PART_BLOCKS, PART_T, 0, stream>>>(esrc, edst, bcur, ebuf);
    csr_bucket_kernel<<<NBK_USED, 512, 0, stream>>>(ebuf, bbase, bcnt, rp, ss);

    fused_sage_kernel<<<NB, 512, 0, stream>>>(xh,  rp, ss, Wt1g, b1, h1h, nullptr);
    fused_sage_kernel<<<NB, 512, 0, stream>>>(h1h, rp, ss, Wt2g, b2, nullptr, out);
}